// Round 2
// baseline (463.797 us; speedup 1.0000x reference)
//
#include <hip/hip_runtime.h>

typedef _Float16 f16;
typedef __attribute__((ext_vector_type(8))) _Float16 f16x8;
typedef __attribute__((ext_vector_type(4))) float f32x4;

#define M2N 131072   // BATCH(4096) * Nc(32)

struct C2 { float x, y; };
__device__ __forceinline__ C2 cmul(C2 a, C2 b){ C2 r; r.x = a.x*b.x - a.y*b.y; r.y = a.x*b.y + a.y*b.x; return r; }
__device__ __forceinline__ C2 cadd(C2 a, C2 b){ C2 r; r.x = a.x+b.x; r.y = a.y+b.y; return r; }
__device__ __forceinline__ C2 csub(C2 a, C2 b){ C2 r; r.x = a.x-b.x; r.y = a.y-b.y; return r; }
__device__ __forceinline__ C2 conjc(C2 a){ C2 r; r.x = a.x; r.y = -a.y; return r; }
__device__ __forceinline__ C2 cneg(C2 a){ C2 r; r.x = -a.x; r.y = -a.y; return r; }
__device__ __forceinline__ float cabs2(C2 a){ return a.x*a.x + a.y*a.y; }
__device__ __forceinline__ float dotr(C2 a, C2 b){ return a.x*b.x + a.y*b.y; }

__device__ __forceinline__ float wred(float v){
  #pragma unroll
  for (int s = 32; s > 0; s >>= 1) v += __shfl_xor(v, s, 64);
  return v;
}

// ---------------------------------------------------------------- prep
// Split W1/W2 into f16 hi+lo, tiled per kh (256 n-rows x 32 k), pre-swizzled
// to LDS-linear order. Layout: wt12s[L][h][kh][n*32 + (kk ^ ((n&3)<<3))]
#define SWW(n, kk) ((n)*32 + ((kk) ^ (((n)&3)<<3)))
__global__ void k_prep(const float* __restrict__ W1, const float* __restrict__ W2,
                       f16* __restrict__ wt12s, float* __restrict__ slots)
{
  const int b = blockIdx.x, tid = threadIdx.x;
  if (b == 16){
    if (tid < 32) slots[tid] = 0.f;
    return;
  }
  const int L = b >> 3, kh = b & 7;
  const float* W = L ? W2 : W1;
  const int n = tid;
  f16* dhi = wt12s + (size_t)L*131072 + (size_t)kh*8192;
  f16* dlo = dhi + (size_t)8*8192;
  #pragma unroll
  for (int kk = 0; kk < 32; ++kk){
    const int k = kh*32 + kk;
    const float w = W[k*256 + n];
    const f16 hi = (f16)w;
    const f16 lo = (f16)(w - (float)hi);
    dhi[SWW(n, kk)] = hi;
    dlo[SWW(n, kk)] = lo;
  }
}

// ---------------------------------------------------------------- F_RF + g2
__global__ void k_frf(const float* __restrict__ H, float2* __restrict__ frf,
                      float2* __restrict__ g2)
{
  const int b2 = blockIdx.x*2 + (threadIdx.x >> 7);
  const int tt = threadIdx.x & 127;
  const int t = tt >> 1, k = tt & 1;
  __shared__ float2 s[2][128];
  const size_t base = ((size_t)(b2*2 + k)*32 + 16)*128;
  const float are = H[base + t];
  const float aim = H[base];
  const float inv = rsqrtf(are*are + aim*aim) * 0.125f;
  float2 v; v.x = are*inv; v.y = -aim*inv;
  frf[((size_t)b2*64 + t)*2 + k] = v;
  s[threadIdx.x >> 7][tt] = v;
  __syncthreads();
  const int w = threadIdx.x >> 6;
  if ((w & 1) == 0){
    const int half = w >> 1;
    const int lane = threadIdx.x & 63;
    const float2 a = s[half][lane*2];
    const float2 b = s[half][lane*2 + 1];
    float re = a.x*b.x + a.y*b.y;          // a * conj(b)
    float im = a.y*b.x - a.x*b.y;
    re = wred(re); im = wred(im);
    if (lane == 0){ float2 g; g.x = re; g.y = im; g2[blockIdx.x*2 + half] = g; }
  }
}

// ---------------------------------------------------------------- H_equ + x
__global__ void k_hequ(const float* __restrict__ H, const float2* __restrict__ frf,
                       float2* __restrict__ hequ, float* __restrict__ x)
{
  const int m2 = blockIdx.x*4 + (threadIdx.x >> 6);
  const int lane = threadIdx.x & 63;
  const int n = m2 >> 12, b2 = m2 & 4095;
  const float4 f = *(const float4*)(frf + ((size_t)b2*64 + lane)*2);
  float accr[2][2], acci[2][2];
  #pragma unroll
  for (int i = 0; i < 2; ++i){
    const float* hr = H + (size_t)(n*8192 + b2*2 + i) * 128;
    const float re = hr[lane];
    const float im = hr[0];
    accr[i][0] = re*f.x - im*f.y;  acci[i][0] = re*f.y + im*f.x;
    accr[i][1] = re*f.z - im*f.w;  acci[i][1] = re*f.w + im*f.z;
  }
  #pragma unroll
  for (int i = 0; i < 2; ++i)
    #pragma unroll
    for (int j = 0; j < 2; ++j){ accr[i][j] = wred(accr[i][j]); acci[i][j] = wred(acci[i][j]); }
  if (lane == 0){
    float pw = 0.f;
    #pragma unroll
    for (int i = 0; i < 2; ++i)
      #pragma unroll
      for (int j = 0; j < 2; ++j) pw += accr[i][j]*accr[i][j] + acci[i][j]*acci[i][j];
    const float rs = rsqrtf(pw);
    *(float4*)(hequ + (size_t)m2*4)     = make_float4(accr[0][0]*rs, acci[0][0]*rs, accr[0][1]*rs, acci[0][1]*rs);
    *(float4*)(hequ + (size_t)m2*4 + 2) = make_float4(accr[1][0]*rs, acci[1][0]*rs, accr[1][1]*rs, acci[1][1]*rs);
    *(float4*)(x + (size_t)m2*8)     = make_float4(accr[0][0]*rs, accr[0][1]*rs, accr[1][0]*rs, accr[1][1]*rs);
    *(float4*)(x + (size_t)m2*8 + 4) = make_float4(acci[0][0]*rs, acci[0][1]*rs, acci[1][0]*rs, acci[1][1]*rs);
  }
}

// ---------------------------------------------------------------- fused MLP
// xa: f32 activations, 128 rows x 256 cols, XOR-swizzled (8-elem groups)
#define SWX(r, c) ((r)*256 + ((c) ^ (((r)&7)<<3)))

__launch_bounds__(512)
__global__ void k_mlp(const float* __restrict__ x, const float* __restrict__ W0,
                      const float* __restrict__ bias0, const f16* __restrict__ wt12s,
                      const float* __restrict__ bias1, const float* __restrict__ bias2,
                      const float* __restrict__ W3, const float* __restrict__ bias3,
                      float* __restrict__ y)
{
  __shared__ __align__(16) float xa[128*256];   // 128 KiB
  __shared__ __align__(16) f16 wt[8192];        // 16 KiB (one 256x32 half-tile)

  const int tid = threadIdx.x;
  const int blk = blockIdx.x;
  const int lane = tid & 63;
  const int wv = tid >> 6;

  // ---- layer 0 (8 -> 256), f32 VALU
  {
    const int nn = tid & 255;
    const int rh = tid >> 8;
    float wr[8];
    #pragma unroll
    for (int e = 0; e < 8; ++e) wr[e] = W0[e*256 + nn];
    const float bb = bias0[nn];
    const float* xs = x + ((size_t)blk*128 + rh*64)*8;
    for (int r = 0; r < 64; ++r){
      const float4 xlo = *(const float4*)(xs + r*8);
      const float4 xhi = *(const float4*)(xs + r*8 + 4);
      float a = bb;
      a += xlo.x*wr[0] + xlo.y*wr[1] + xlo.z*wr[2] + xlo.w*wr[3];
      a += xhi.x*wr[4] + xhi.y*wr[5] + xhi.z*wr[6] + xhi.w*wr[7];
      xa[SWX(rh*64 + r, nn)] = fmaxf(a, 0.f);
    }
  }

  // ---- layers 1,2 (256 -> 256), split-f16 3-product MFMA
  for (int L = 0; L < 2; ++L){
    const float* bs = L ? bias2 : bias1;
    const f16* wsrc = wt12s + (size_t)L*131072;
    f32x4 acc[16];
    #pragma unroll
    for (int nt = 0; nt < 16; ++nt){
      const float bb = bs[nt*16 + (lane & 15)];
      f32x4 v = {bb, bb, bb, bb};
      acc[nt] = v;
    }
    for (int kh = 0; kh < 8; ++kh){
      __syncthreads();
      #pragma unroll
      for (int c = 0; c < 2; ++c){    // stage hi tile (256x32 f16, pre-swizzled)
        const int idx = c*512 + tid;
        *(f16x8*)(wt + idx*8) = *(const f16x8*)(wsrc + (size_t)kh*8192 + (size_t)idx*8);
      }
      __syncthreads();
      // A fragment: read f32, exact hi/lo split
      const int arow = wv*16 + (lane & 15);
      const int cbase = kh*32 + (lane >> 4)*8;
      f16x8 ah, al;
      {
        const float4 v0 = *(const float4*)(xa + SWX(arow, cbase));
        const float4 v1 = *(const float4*)(xa + SWX(arow, cbase + 4));
        const float vv[8] = {v0.x, v0.y, v0.z, v0.w, v1.x, v1.y, v1.z, v1.w};
        #pragma unroll
        for (int e = 0; e < 8; ++e){
          const f16 h16 = (f16)vv[e];
          ah[e] = h16;
          al[e] = (f16)(vv[e] - (float)h16);
        }
      }
      const int kb = (lane >> 4)*8;
      #pragma unroll
      for (int nt = 0; nt < 16; ++nt){
        const int brow = nt*16 + (lane & 15);
        const f16x8 bh = *(const f16x8*)(wt + SWW(brow, kb));
        acc[nt] = __builtin_amdgcn_mfma_f32_16x16x32_f16(ah, bh, acc[nt], 0, 0, 0);
        acc[nt] = __builtin_amdgcn_mfma_f32_16x16x32_f16(al, bh, acc[nt], 0, 0, 0);
      }
      __syncthreads();
      #pragma unroll
      for (int c = 0; c < 2; ++c){    // stage lo tile
        const int idx = c*512 + tid;
        *(f16x8*)(wt + idx*8) = *(const f16x8*)(wsrc + (size_t)(8 + kh)*8192 + (size_t)idx*8);
      }
      __syncthreads();
      #pragma unroll
      for (int nt = 0; nt < 16; ++nt){
        const int brow = nt*16 + (lane & 15);
        const f16x8 bl = *(const f16x8*)(wt + SWW(brow, kb));
        acc[nt] = __builtin_amdgcn_mfma_f32_16x16x32_f16(ah, bl, acc[nt], 0, 0, 0);
      }
    }
    __syncthreads();
    #pragma unroll
    for (int nt = 0; nt < 16; ++nt){   // epilogue: relu, f32 back to xa (own rows)
      const int cc = nt*16 + (lane & 15);
      #pragma unroll
      for (int rr = 0; rr < 4; ++rr){
        const int row = wv*16 + (lane >> 4)*4 + rr;
        xa[SWX(row, cc)] = fmaxf(acc[nt][rr], 0.f);
      }
    }
  }
  __syncthreads();

  // ---- layer 3 (256 -> 8), f32 VALU
  {
    float* w3s = (float*)wt;                 // 8 KiB: W3 copied verbatim [k][j]
    ((float4*)w3s)[tid] = ((const float4*)W3)[tid];
  }
  __syncthreads();
  {
    const float* w3s = (const float*)wt;
    const int r = tid >> 2;
    const int q = tid & 3;
    float a0 = bias3[q*2];
    float a1 = bias3[q*2 + 1];
    for (int k8 = 0; k8 < 32; ++k8){
      const float4 xv0 = *(const float4*)(xa + SWX(r, k8*8));
      const float4 xv1 = *(const float4*)(xa + SWX(r, k8*8 + 4));
      const float xv[8] = {xv0.x, xv0.y, xv0.z, xv0.w, xv1.x, xv1.y, xv1.z, xv1.w};
      #pragma unroll
      for (int e = 0; e < 8; ++e){
        const int k = k8*8 + e;
        a0 += xv[e]*w3s[k*8 + q*2];
        a1 += xv[e]*w3s[k*8 + q*2 + 1];
      }
    }
    float2 o; o.x = a0; o.y = a1;
    *(float2*)(y + ((size_t)blk*128 + r)*8 + q*2) = o;
  }
}

// ---------------------------------------------------------------- per-element algebra
struct Elem {
  C2 p[2][2], g[2][2], UW[2], d0, d1;
  float A0, A1, A2, c0, c1, c2, c3;
};

__device__ __forceinline__ void elem_core(const float2* __restrict__ hequ,
                                          const float* __restrict__ y,
                                          int gid, Elem& E)
{
  const float4 h0 = *(const float4*)(hequ + (size_t)gid*4);
  const float4 h1 = *(const float4*)(hequ + (size_t)gid*4 + 2);
  C2 h[2][2];
  h[0][0].x = h0.x; h[0][0].y = h0.y; h[0][1].x = h0.z; h[0][1].y = h0.w;
  h[1][0].x = h1.x; h[1][0].y = h1.y; h[1][1].x = h1.z; h[1][1].y = h1.w;
  const float4 ya = *(const float4*)(y + (size_t)gid*8);
  const float4 yb = *(const float4*)(y + (size_t)gid*8 + 4);
  C2 U[2], Wm[2];
  U[0].x = ya.x; U[0].y = ya.z;  U[1].x = ya.y; U[1].y = ya.w;
  Wm[0].x = yb.x; Wm[0].y = yb.z; Wm[1].x = yb.y; Wm[1].y = yb.w;
  const float u20 = cabs2(U[0]), u21 = cabs2(U[1]);
  C2 cf[2];
  cf[0].x = Wm[0].x*u20; cf[0].y = Wm[0].y*u20;
  cf[1].x = Wm[1].x*u21; cf[1].y = Wm[1].y*u21;
  C2 B[2][2];
  #pragma unroll
  for (int i = 0; i < 2; ++i)
    #pragma unroll
    for (int j = 0; j < 2; ++j){
      const C2 t0 = cmul(conjc(h[0][i]), h[0][j]);
      const C2 t1 = cmul(conjc(h[1][i]), h[1][j]);
      B[i][j] = cadd(cmul(cf[0], t0), cmul(cf[1], t1));
    }
  C2 adj[2][2];
  adj[0][0] = B[1][1]; adj[0][1] = cneg(B[0][1]);
  adj[1][0] = cneg(B[1][0]); adj[1][1] = B[0][0];
  E.d0 = csub(cmul(B[0][0], B[1][1]), cmul(B[0][1], B[1][0]));
  E.d1.x = 2.f*(B[0][0].x + B[1][1].x);
  E.d1.y = 2.f*(B[0][0].y + B[1][1].y);
  #pragma unroll
  for (int k = 0; k < 2; ++k){
    #pragma unroll
    for (int j = 0; j < 2; ++j) E.g[k][j] = conjc(h[k][j]);
    #pragma unroll
    for (int i = 0; i < 2; ++i)
      E.p[k][i] = cadd(cmul(adj[i][0], E.g[k][0]), cmul(adj[i][1], E.g[k][1]));
    E.UW[k] = cmul(U[k], Wm[k]);
  }
  const float w0 = cabs2(E.UW[0]), w1 = cabs2(E.UW[1]);
  E.A0 = w0*(cabs2(E.p[0][0]) + cabs2(E.p[0][1])) + w1*(cabs2(E.p[1][0]) + cabs2(E.p[1][1]));
  E.A1 = 4.f*( w0*(dotr(E.p[0][0], E.g[0][0]) + dotr(E.p[0][1], E.g[0][1]))
             + w1*(dotr(E.p[1][0], E.g[1][0]) + dotr(E.p[1][1], E.g[1][1])) );
  E.A2 = 4.f*( w0*(cabs2(E.g[0][0]) + cabs2(E.g[0][1]))
             + w1*(cabs2(E.g[1][0]) + cabs2(E.g[1][1])) );
  E.c0 = cabs2(E.d0);
  E.c1 = 2.f*(E.d0.x*E.d1.x + E.d0.y*E.d1.y);
  E.c2 = cabs2(E.d1) + 8.f*E.d0.x;
  E.c3 = 8.f*E.d1.x;
}

__global__ void k_coef(const float2* __restrict__ hequ, const float* __restrict__ y,
                       float* __restrict__ coef)
{
  const int gid = blockIdx.x*256 + threadIdx.x;
  Elem E;
  elem_core(hequ, y, gid, E);
  *(float4*)(coef + (size_t)gid*8)     = make_float4(E.A0, E.A1, E.A2, E.c0);
  *(float4*)(coef + (size_t)gid*8 + 4) = make_float4(E.c1, E.c2, E.c3, 0.f);
}

__global__ void k_biter(const float* __restrict__ coef, float* __restrict__ slots, int it)
{
  const int gid = blockIdx.x*256 + threadIdx.x;
  const float4 a = *(const float4*)(coef + (size_t)gid*8);
  const float4 b = *(const float4*)(coef + (size_t)gid*8 + 4);
  float lo = 0.f, hi = 10.f;
  for (int j = 0; j < it; ++j){
    const float mu = 0.5f*(lo + hi);
    if (slots[j] > 1.0f) lo = mu; else hi = mu;
  }
  const float mu = 0.5f*(lo + hi);
  const float num = a.x + mu*(a.y + mu*a.z);
  const float den = a.w + mu*(b.x + mu*(b.y + mu*(b.z + mu*16.f)));
  float f = num/den;
  f = wred(f);
  __shared__ float r4[4];
  if ((threadIdx.x & 63) == 0) r4[threadIdx.x >> 6] = f;
  __syncthreads();
  if (threadIdx.x == 0) atomicAdd(&slots[it], r4[0] + r4[1] + r4[2] + r4[3]);
}

__global__ void k_final(const float2* __restrict__ hequ, const float* __restrict__ y,
                        const float2* __restrict__ g2, const float* __restrict__ slots,
                        float2* __restrict__ V, float* __restrict__ Pm)
{
  const int gid = blockIdx.x*256 + threadIdx.x;
  Elem E;
  elem_core(hequ, y, gid, E);
  float lo = 0.f, hi = 10.f;
  for (int j = 0; j < 19; ++j){
    const float mu = 0.5f*(lo + hi);
    if (slots[j] > 1.0f) lo = mu; else hi = mu;
  }
  const float mu = 0.5f*(lo + hi);
  C2 det; det.x = E.d0.x + mu*E.d1.x + 4.f*mu*mu; det.y = E.d0.y + mu*E.d1.y;
  const float id = 1.f/cabs2(det);
  C2 idet; idet.x = det.x*id; idet.y = -det.y*id;
  C2 Vv[2][2];
  #pragma unroll
  for (int k = 0; k < 2; ++k)
    #pragma unroll
    for (int i = 0; i < 2; ++i){
      C2 t; t.x = E.p[k][i].x + 2.f*mu*E.g[k][i].x; t.y = E.p[k][i].y + 2.f*mu*E.g[k][i].y;
      Vv[i][k] = cmul(E.UW[k], cmul(t, idet));
    }
  *(float4*)(V + (size_t)gid*4)     = make_float4(Vv[0][0].x, Vv[0][0].y, Vv[0][1].x, Vv[0][1].y);
  *(float4*)(V + (size_t)gid*4 + 2) = make_float4(Vv[1][0].x, Vv[1][0].y, Vv[1][1].x, Vv[1][1].y);
  const float2 gg2 = g2[gid & 4095];
  C2 gg; gg.x = gg2.x; gg.y = gg2.y;
  float P = 0.f;
  #pragma unroll
  for (int k = 0; k < 2; ++k){
    const C2 a = Vv[0][k], b = Vv[1][k];
    P += cabs2(a) + cabs2(b);
    const C2 t = cmul(gg, cmul(a, conjc(b)));
    P += 2.f*t.x;
  }
  Pm[gid] = P;
}

// ---------------------------------------------------------------- output
__global__ void k_out(const float2* __restrict__ frf, const float2* __restrict__ V,
                      const float* __restrict__ Pm, float* __restrict__ out)
{
  const int b2 = blockIdx.x;
  const int t = threadIdx.x & 63;
  const int ng = threadIdx.x >> 6;
  const float4 f = *(const float4*)(frf + ((size_t)b2*64 + t)*2);
  C2 f0, f1; f0.x = f.x; f0.y = f.y; f1.x = f.z; f1.y = f.w;
  for (int n = ng; n < 32; n += 4){
    const float4* mv = (const float4*)(V + ((size_t)n*4096 + b2)*4);
    const float4 m0 = mv[0];
    const float4 m1 = mv[1];
    C2 M00, M01, M10, M11;
    M00.x = m0.x; M00.y = m0.y; M01.x = m0.z; M01.y = m0.w;
    M10.x = m1.x; M10.y = m1.y; M11.x = m1.z; M11.y = m1.w;
    const float sc = 1.41421356237f * rsqrtf(Pm[b2*32 + n]);
    const C2 c0 = cadd(cmul(f0, M00), cmul(f1, M10));
    const C2 c1 = cadd(cmul(f0, M01), cmul(f1, M11));
    const size_t base = (size_t)b2*8192 + n*128 + t*2;
    *(float2*)(out + base)        = make_float2(c0.x*sc, c1.x*sc);
    *(float2*)(out + base + 4096) = make_float2(c0.y*sc, c1.y*sc);
  }
}

// ---------------------------------------------------------------- launch
extern "C" void kernel_launch(void* const* d_in, const int* in_sizes, int n_in,
                              void* d_out, int out_size, void* d_ws, size_t ws_size,
                              hipStream_t stream)
{
  const float* H  = (const float*)d_in[0];
  const float* W0 = (const float*)d_in[1];
  const float* b0 = (const float*)d_in[2];
  const float* W1 = (const float*)d_in[3];
  const float* b1 = (const float*)d_in[4];
  const float* W2 = (const float*)d_in[5];
  const float* b2 = (const float*)d_in[6];
  const float* W3 = (const float*)d_in[7];
  const float* b3 = (const float*)d_in[8];
  float* out = (float*)d_out;
  char* ws = (char*)d_ws;
  (void)in_sizes; (void)n_in; (void)out_size; (void)ws_size;

  size_t o = 0;
  auto alloc = [&](size_t bytes) -> void* {
    void* p = ws + o;
    o += (bytes + 255) & ~(size_t)255;
    return p;
  };
  float2* frf   = (float2*)alloc((size_t)4096*64*2*sizeof(float2)); // 4 MiB
  float2* g2    = (float2*)alloc((size_t)4096*sizeof(float2));
  float2* hequ  = (float2*)alloc((size_t)M2N*4*sizeof(float2));     // 4 MiB
  float*  xbuf  = (float*) alloc((size_t)M2N*8*sizeof(float));      // 4 MiB
  float*  ybuf  = (float*) alloc((size_t)M2N*8*sizeof(float));      // 4 MiB
  float*  coef  = (float*) alloc((size_t)M2N*8*sizeof(float));      // 4 MiB
  float2* V     = (float2*)alloc((size_t)M2N*4*sizeof(float2));     // 4 MiB
  float*  Pm    = (float*) alloc((size_t)M2N*sizeof(float));        // 0.5 MiB
  float*  slots = (float*) alloc(32*sizeof(float));
  f16*    wt12s = (f16*)   alloc((size_t)4*65536*sizeof(f16));      // 512 KiB

  k_prep<<<17, 256, 0, stream>>>(W1, W2, wt12s, slots);
  k_frf<<<2048, 256, 0, stream>>>(H, frf, g2);
  k_hequ<<<32768, 256, 0, stream>>>(H, frf, hequ, xbuf);
  k_mlp<<<1024, 512, 0, stream>>>(xbuf, W0, b0, wt12s, b1, b2, W3, b3, ybuf);
  k_coef<<<512, 256, 0, stream>>>(hequ, ybuf, coef);
  for (int it = 0; it < 19; ++it)
    k_biter<<<512, 256, 0, stream>>>(coef, slots, it);
  k_final<<<512, 256, 0, stream>>>(hequ, ybuf, g2, slots, V, Pm);
  k_out<<<4096, 256, 0, stream>>>(frf, V, Pm, out);
}

// Round 3
// 444.993 us; speedup vs baseline: 1.0423x; 1.0423x over previous
//
#include <hip/hip_runtime.h>
#include <hip/hip_cooperative_groups.h>

namespace cg = cooperative_groups;

typedef _Float16 f16;
typedef __attribute__((ext_vector_type(8))) _Float16 f16x8;
typedef __attribute__((ext_vector_type(4))) float f32x4;
typedef unsigned int u32;

#define M2N 131072   // BATCH(4096) * Nc(32)
#define MFMA16 __builtin_amdgcn_mfma_f32_16x16x32_f16

struct C2 { float x, y; };
__device__ __forceinline__ C2 cmul(C2 a, C2 b){ C2 r; r.x = a.x*b.x - a.y*b.y; r.y = a.x*b.y + a.y*b.x; return r; }
__device__ __forceinline__ C2 cadd(C2 a, C2 b){ C2 r; r.x = a.x+b.x; r.y = a.y+b.y; return r; }
__device__ __forceinline__ C2 csub(C2 a, C2 b){ C2 r; r.x = a.x-b.x; r.y = a.y-b.y; return r; }
__device__ __forceinline__ C2 conjc(C2 a){ C2 r; r.x = a.x; r.y = -a.y; return r; }
__device__ __forceinline__ C2 cneg(C2 a){ C2 r; r.x = -a.x; r.y = -a.y; return r; }
__device__ __forceinline__ float cabs2(C2 a){ return a.x*a.x + a.y*a.y; }
__device__ __forceinline__ float dotr(C2 a, C2 b){ return a.x*b.x + a.y*b.y; }

__device__ __forceinline__ float wred(float v){
  #pragma unroll
  for (int s = 32; s > 0; s >>= 1) v += __shfl_xor(v, s, 64);
  return v;
}

// ---------------------------------------------------------------- prep
// Build frag-linear hi/lo f16 weight fragments for 16x16x32 MFMA.
// B-frag: lane l holds B[k = kt*32 + (l>>4)*8 + e][n = nt*16 + (l&15)].
// wfr12: [L(2)][nt(16)][kt(8)] x [hi 512 f16][lo 512 f16]
// wfr0 : [nt(16)] x [hi 512][lo 512]   (K=32 padded, real k<8)
// wfr3 : [kt(8)]  x [hi 512][lo 512]   (N=16 padded, real n<8)
__global__ void k_prep(const float* __restrict__ W0, const float* __restrict__ W1,
                       const float* __restrict__ W2, const float* __restrict__ W3,
                       f16* __restrict__ wfr12, f16* __restrict__ wfr0,
                       f16* __restrict__ wfr3)
{
  const int b = blockIdx.x, tid = threadIdx.x;
  if (b < 64){
    const int slot = b*256 + tid;        // [0, 16384)
    const int lane = slot & 63;
    const int rest = slot >> 6;          // L*128 + nt*8 + kt
    const int kt = rest & 7, nt = (rest >> 3) & 15, L = rest >> 7;
    const float* W = L ? W2 : W1;
    const int n = nt*16 + (lane & 15);
    f16* dst = wfr12 + (size_t)rest*1024 + lane*8;
    #pragma unroll
    for (int e = 0; e < 8; ++e){
      const int k = kt*32 + (lane>>4)*8 + e;
      const float w = W[k*256 + n];
      const f16 h = (f16)w;
      dst[e] = h; dst[512+e] = (f16)(w - (float)h);
    }
  } else if (b == 64){
    for (int i = 0; i < 4; ++i){
      const int slot = i*256 + tid;      // [0,1024)
      const int lane = slot & 63, nt = slot >> 6;
      const int col = nt*16 + (lane & 15);
      f16* dst = wfr0 + (size_t)nt*1024 + lane*8;
      #pragma unroll
      for (int e = 0; e < 8; ++e){
        const int k = (lane>>4)*8 + e;
        const float w = (k < 8) ? W0[k*256 + col] : 0.f;
        const f16 h = (f16)w;
        dst[e] = h; dst[512+e] = (f16)(w - (float)h);
      }
    }
  } else {
    for (int i = 0; i < 2; ++i){
      const int slot = i*256 + tid;      // [0,512)
      const int lane = slot & 63, kt = slot >> 6;
      const int col = lane & 15;
      f16* dst = wfr3 + (size_t)kt*1024 + lane*8;
      #pragma unroll
      for (int e = 0; e < 8; ++e){
        const int k = kt*32 + (lane>>4)*8 + e;
        const float w = (col < 8) ? W3[k*8 + col] : 0.f;
        const f16 h = (f16)w;
        dst[e] = h; dst[512+e] = (f16)(w - (float)h);
      }
    }
  }
}

// ---------------------------------------------------------------- F_RF + g2
__global__ void k_frf(const float* __restrict__ H, float2* __restrict__ frf,
                      float2* __restrict__ g2)
{
  const int b2 = blockIdx.x*2 + (threadIdx.x >> 7);
  const int tt = threadIdx.x & 127;
  const int t = tt >> 1, k = tt & 1;
  __shared__ float2 s[2][128];
  const size_t base = ((size_t)(b2*2 + k)*32 + 16)*128;
  const float are = H[base + t];
  const float aim = H[base];
  const float inv = rsqrtf(are*are + aim*aim) * 0.125f;
  float2 v; v.x = are*inv; v.y = -aim*inv;
  frf[((size_t)b2*64 + t)*2 + k] = v;
  s[threadIdx.x >> 7][tt] = v;
  __syncthreads();
  const int w = threadIdx.x >> 6;
  if ((w & 1) == 0){
    const int half = w >> 1;
    const int lane = threadIdx.x & 63;
    const float2 a = s[half][lane*2];
    const float2 b = s[half][lane*2 + 1];
    float re = a.x*b.x + a.y*b.y;          // a * conj(b)
    float im = a.y*b.x - a.x*b.y;
    re = wred(re); im = wred(im);
    if (lane == 0){ float2 g; g.x = re; g.y = im; g2[blockIdx.x*2 + half] = g; }
  }
}

// ---------------------------------------------------------------- H_equ -> x
__global__ void k_hequ(const float* __restrict__ H, const float2* __restrict__ frf,
                       float* __restrict__ x)
{
  const int m2 = blockIdx.x*4 + (threadIdx.x >> 6);
  const int lane = threadIdx.x & 63;
  const int n = m2 >> 12, b2 = m2 & 4095;
  const float4 f = *(const float4*)(frf + ((size_t)b2*64 + lane)*2);
  float accr[2][2], acci[2][2];
  #pragma unroll
  for (int i = 0; i < 2; ++i){
    const float* hr = H + (size_t)(n*8192 + b2*2 + i) * 128;
    const float re = hr[lane];
    const float im = hr[0];
    accr[i][0] = re*f.x - im*f.y;  acci[i][0] = re*f.y + im*f.x;
    accr[i][1] = re*f.z - im*f.w;  acci[i][1] = re*f.w + im*f.z;
  }
  #pragma unroll
  for (int i = 0; i < 2; ++i)
    #pragma unroll
    for (int j = 0; j < 2; ++j){ accr[i][j] = wred(accr[i][j]); acci[i][j] = wred(acci[i][j]); }
  if (lane == 0){
    float pw = 0.f;
    #pragma unroll
    for (int i = 0; i < 2; ++i)
      #pragma unroll
      for (int j = 0; j < 2; ++j) pw += accr[i][j]*accr[i][j] + acci[i][j]*acci[i][j];
    const float rs = rsqrtf(pw);
    *(float4*)(x + (size_t)m2*8)     = make_float4(accr[0][0]*rs, accr[0][1]*rs, accr[1][0]*rs, accr[1][1]*rs);
    *(float4*)(x + (size_t)m2*8 + 4) = make_float4(acci[0][0]*rs, acci[0][1]*rs, acci[1][0]*rs, acci[1][1]*rs);
  }
}

// ---------------------------------------------------------------- fused MLP
// 64-row blocks, 256 thr (4 waves, wave = 64r x 64c). Activations in LDS as
// u32 = (lo16<<16)|hi16 exact f16 split. B-frags from global (frag-linear).
__device__ __forceinline__ void unpack8(uint4 q0, uint4 q1, f16x8& ah, f16x8& al){
  union UU { uint4 u; f16x8 f; } Hh, Ll;
  Hh.u.x = __builtin_amdgcn_perm(q0.y, q0.x, 0x05040100u);
  Hh.u.y = __builtin_amdgcn_perm(q0.w, q0.z, 0x05040100u);
  Hh.u.z = __builtin_amdgcn_perm(q1.y, q1.x, 0x05040100u);
  Hh.u.w = __builtin_amdgcn_perm(q1.w, q1.z, 0x05040100u);
  Ll.u.x = __builtin_amdgcn_perm(q0.y, q0.x, 0x07060302u);
  Ll.u.y = __builtin_amdgcn_perm(q0.w, q0.z, 0x07060302u);
  Ll.u.z = __builtin_amdgcn_perm(q1.y, q1.x, 0x07060302u);
  Ll.u.w = __builtin_amdgcn_perm(q1.w, q1.z, 0x07060302u);
  ah = Hh.f; al = Ll.f;
}

__launch_bounds__(256, 2)
__global__ void k_mlp(const float* __restrict__ x, const f16* __restrict__ wfr12,
                      const f16* __restrict__ wfr0, const f16* __restrict__ wfr3,
                      const float* __restrict__ bias0, const float* __restrict__ bias1,
                      const float* __restrict__ bias2, const float* __restrict__ bias3,
                      float* __restrict__ y)
{
  __shared__ u32 xa[64*256];   // 64 KiB -> 2 blocks/CU
  const int tid = threadIdx.x, blk = blockIdx.x;
  const int lane = tid & 63, wv = tid >> 6;
  const int l15 = lane & 15, lh = lane >> 4;

  f32x4 acc[4][4];
  f16x8 ah[4], al[4], bh[4], bl[4];

  auto EPI = [&](){   // relu + exact f16 split + pack + swizzled LDS write
    #pragma unroll
    for (int Mt = 0; Mt < 4; ++Mt)
      #pragma unroll
      for (int nt = 0; nt < 4; ++nt)
        #pragma unroll
        for (int r = 0; r < 4; ++r){
          const float v = fmaxf(acc[Mt][nt][r], 0.f);
          const f16 h = (f16)v;
          const f16 lo16 = (f16)(v - (float)h);
          const u32 p = (u32)__builtin_bit_cast(unsigned short, h)
                      | ((u32)__builtin_bit_cast(unsigned short, lo16) << 16);
          const int row = Mt*16 + lh*4 + r;
          const int col = wv*64 + nt*16 + l15;
          xa[row*256 + (col ^ ((row&7)<<2))] = p;
        }
  };

  // ---------- layer 0 (8 -> 256, K padded to 32; zero-padded B kills garbage A)
  #pragma unroll
  for (int nt = 0; nt < 4; ++nt){
    const float bb = bias0[wv*64 + nt*16 + l15];
    f32x4 v = {bb,bb,bb,bb};
    #pragma unroll
    for (int Mt = 0; Mt < 4; ++Mt) acc[Mt][nt] = v;
  }
  #pragma unroll
  for (int Mt = 0; Mt < 4; ++Mt){
    const float* xr = x + ((size_t)blk*64 + Mt*16 + l15)*8;
    const float4 v0 = *(const float4*)xr;
    const float4 v1 = *(const float4*)(xr+4);
    const float vv[8] = {v0.x,v0.y,v0.z,v0.w,v1.x,v1.y,v1.z,v1.w};
    #pragma unroll
    for (int e = 0; e < 8; ++e){
      const f16 h = (f16)vv[e];
      ah[Mt][e] = h; al[Mt][e] = (f16)(vv[e] - (float)h);
    }
  }
  #pragma unroll
  for (int nt = 0; nt < 4; ++nt){
    bh[nt] = *(const f16x8*)(wfr0 + (size_t)(wv*4+nt)*1024 + lane*8);
    bl[nt] = *(const f16x8*)(wfr0 + (size_t)(wv*4+nt)*1024 + 512 + lane*8);
  }
  #pragma unroll
  for (int Mt = 0; Mt < 4; ++Mt)
    #pragma unroll
    for (int nt = 0; nt < 4; ++nt){
      acc[Mt][nt] = MFMA16(ah[Mt], bh[nt], acc[Mt][nt], 0, 0, 0);
      acc[Mt][nt] = MFMA16(al[Mt], bh[nt], acc[Mt][nt], 0, 0, 0);
      acc[Mt][nt] = MFMA16(ah[Mt], bl[nt], acc[Mt][nt], 0, 0, 0);
    }
  EPI();
  __syncthreads();

  // ---------- layers 1,2 (256 -> 256)
  for (int L = 0; L < 2; ++L){
    const float* bs = L ? bias2 : bias1;
    #pragma unroll
    for (int nt = 0; nt < 4; ++nt){
      const float bb = bs[wv*64 + nt*16 + l15];
      f32x4 v = {bb,bb,bb,bb};
      #pragma unroll
      for (int Mt = 0; Mt < 4; ++Mt) acc[Mt][nt] = v;
    }
    #pragma unroll 1
    for (int kt = 0; kt < 8; ++kt){
      #pragma unroll
      for (int Mt = 0; Mt < 4; ++Mt){
        const int row = Mt*16 + l15;
        const int cb = kt*32 + lh*8;
        const int sw = (row&7)<<2;
        const uint4 q0 = *(const uint4*)(xa + row*256 + (cb ^ sw));
        const uint4 q1 = *(const uint4*)(xa + row*256 + ((cb+4) ^ sw));
        unpack8(q0, q1, ah[Mt], al[Mt]);
      }
      #pragma unroll
      for (int nt = 0; nt < 4; ++nt){
        const size_t f = ((size_t)(L*128 + (wv*4+nt)*8 + kt))*1024;
        bh[nt] = *(const f16x8*)(wfr12 + f + lane*8);
        bl[nt] = *(const f16x8*)(wfr12 + f + 512 + lane*8);
      }
      #pragma unroll
      for (int Mt = 0; Mt < 4; ++Mt)
        #pragma unroll
        for (int nt = 0; nt < 4; ++nt){
          acc[Mt][nt] = MFMA16(ah[Mt], bh[nt], acc[Mt][nt], 0, 0, 0);
          acc[Mt][nt] = MFMA16(al[Mt], bh[nt], acc[Mt][nt], 0, 0, 0);
          acc[Mt][nt] = MFMA16(ah[Mt], bl[nt], acc[Mt][nt], 0, 0, 0);
        }
    }
    __syncthreads();   // all reads done before overwrite
    EPI();
    __syncthreads();
  }

  // ---------- layer 3 (256 -> 8, N padded to 16; zero-padded B cols)
  f32x4 a3[4];
  {
    const float bb = (l15 < 8) ? bias3[l15] : 0.f;
    f32x4 v = {bb,bb,bb,bb};
    #pragma unroll
    for (int Mt = 0; Mt < 4; ++Mt) a3[Mt] = v;
  }
  #pragma unroll 1
  for (int kt = 0; kt < 8; ++kt){
    #pragma unroll
    for (int Mt = 0; Mt < 4; ++Mt){
      const int row = Mt*16 + l15;
      const int cb = kt*32 + lh*8;
      const int sw = (row&7)<<2;
      const uint4 q0 = *(const uint4*)(xa + row*256 + (cb ^ sw));
      const uint4 q1 = *(const uint4*)(xa + row*256 + ((cb+4) ^ sw));
      unpack8(q0, q1, ah[Mt], al[Mt]);
    }
    const f16x8 b3h = *(const f16x8*)(wfr3 + (size_t)kt*1024 + lane*8);
    const f16x8 b3l = *(const f16x8*)(wfr3 + (size_t)kt*1024 + 512 + lane*8);
    #pragma unroll
    for (int Mt = 0; Mt < 4; ++Mt){
      a3[Mt] = MFMA16(ah[Mt], b3h, a3[Mt], 0, 0, 0);
      a3[Mt] = MFMA16(al[Mt], b3h, a3[Mt], 0, 0, 0);
      a3[Mt] = MFMA16(ah[Mt], b3l, a3[Mt], 0, 0, 0);
    }
  }
  if (l15 < 8){
    #pragma unroll
    for (int Mt = 0; Mt < 4; ++Mt)
      #pragma unroll
      for (int r = 0; r < 4; ++r)
        y[((size_t)blk*64 + Mt*16 + lh*4 + r)*8 + l15] = a3[Mt][r];
  }
}

// ---------------------------------------------------------------- per-element algebra
struct Elem {
  C2 p[2][2], g[2][2], UW[2], d0, d1;
  float A0, A1, A2, c0, c1, c2, c3;
};

__device__ __forceinline__ void elem_core(const float* __restrict__ x,
                                          const float* __restrict__ y,
                                          int gid, Elem& E)
{
  const float4 xr = *(const float4*)(x + (size_t)gid*8);
  const float4 xi = *(const float4*)(x + (size_t)gid*8 + 4);
  C2 h[2][2];
  h[0][0].x = xr.x; h[0][0].y = xi.x; h[0][1].x = xr.y; h[0][1].y = xi.y;
  h[1][0].x = xr.z; h[1][0].y = xi.z; h[1][1].x = xr.w; h[1][1].y = xi.w;
  const float4 ya = *(const float4*)(y + (size_t)gid*8);
  const float4 yb = *(const float4*)(y + (size_t)gid*8 + 4);
  C2 U[2], Wm[2];
  U[0].x = ya.x; U[0].y = ya.z;  U[1].x = ya.y; U[1].y = ya.w;
  Wm[0].x = yb.x; Wm[0].y = yb.z; Wm[1].x = yb.y; Wm[1].y = yb.w;
  const float u20 = cabs2(U[0]), u21 = cabs2(U[1]);
  C2 cf[2];
  cf[0].x = Wm[0].x*u20; cf[0].y = Wm[0].y*u20;
  cf[1].x = Wm[1].x*u21; cf[1].y = Wm[1].y*u21;
  C2 B[2][2];
  #pragma unroll
  for (int i = 0; i < 2; ++i)
    #pragma unroll
    for (int j = 0; j < 2; ++j){
      const C2 t0 = cmul(conjc(h[0][i]), h[0][j]);
      const C2 t1 = cmul(conjc(h[1][i]), h[1][j]);
      B[i][j] = cadd(cmul(cf[0], t0), cmul(cf[1], t1));
    }
  C2 adj[2][2];
  adj[0][0] = B[1][1]; adj[0][1] = cneg(B[0][1]);
  adj[1][0] = cneg(B[1][0]); adj[1][1] = B[0][0];
  E.d0 = csub(cmul(B[0][0], B[1][1]), cmul(B[0][1], B[1][0]));
  E.d1.x = 2.f*(B[0][0].x + B[1][1].x);
  E.d1.y = 2.f*(B[0][0].y + B[1][1].y);
  #pragma unroll
  for (int k = 0; k < 2; ++k){
    #pragma unroll
    for (int j = 0; j < 2; ++j) E.g[k][j] = conjc(h[k][j]);
    #pragma unroll
    for (int i = 0; i < 2; ++i)
      E.p[k][i] = cadd(cmul(adj[i][0], E.g[k][0]), cmul(adj[i][1], E.g[k][1]));
    E.UW[k] = cmul(U[k], Wm[k]);
  }
  const float w0 = cabs2(E.UW[0]), w1 = cabs2(E.UW[1]);
  E.A0 = w0*(cabs2(E.p[0][0]) + cabs2(E.p[0][1])) + w1*(cabs2(E.p[1][0]) + cabs2(E.p[1][1]));
  E.A1 = 4.f*( w0*(dotr(E.p[0][0], E.g[0][0]) + dotr(E.p[0][1], E.g[0][1]))
             + w1*(dotr(E.p[1][0], E.g[1][0]) + dotr(E.p[1][1], E.g[1][1])) );
  E.A2 = 4.f*( w0*(cabs2(E.g[0][0]) + cabs2(E.g[0][1]))
             + w1*(cabs2(E.g[1][0]) + cabs2(E.g[1][1])) );
  E.c0 = cabs2(E.d0);
  E.c1 = 2.f*(E.d0.x*E.d1.x + E.d0.y*E.d1.y);
  E.c2 = cabs2(E.d1) + 8.f*E.d0.x;
  E.c3 = 8.f*E.d1.x;
}

// ---------------------------------------------------------------- fused bisection solve
// Cooperative: 256 blocks x 512 thr. 3 bisection levels per grid sync
// (7 candidate mus = exact f32 midpoints of the decision tree), 7 syncs for
// 19 decisions. Double-buffered block partials; every block redundantly
// reduces all 256 partials with an identical deterministic tree.
__global__ void k_solve(const float* __restrict__ x, const float* __restrict__ y,
                        const float2* __restrict__ g2, float* __restrict__ pr,
                        float2* __restrict__ V, float* __restrict__ Pm)
{
  cg::grid_group gg = cg::this_grid();
  const int gid = blockIdx.x*512 + threadIdx.x;
  const int lane = threadIdx.x & 63, nwv = threadIdx.x >> 6;
  Elem E;
  elem_core(x, y, gid, E);
  __shared__ float r8[8][8];

  float lo = 0.f, hi = 10.f;
  for (int round = 0; round < 7; ++round){
    const int nc = (round < 6) ? 7 : 1;
    float c[7];
    const float m1 = 0.5f*(lo + hi);
    c[0] = m1;
    if (nc == 7){
      const float cl = 0.5f*(lo + m1), ch = 0.5f*(m1 + hi);
      c[1] = cl; c[2] = ch;
      c[3] = 0.5f*(lo + cl); c[4] = 0.5f*(cl + m1);
      c[5] = 0.5f*(m1 + ch); c[6] = 0.5f*(ch + hi);
    }
    // per-wave partial sums of f(mu_q)
    for (int q = 0; q < nc; ++q){
      const float mu = c[q];
      const float num = E.A0 + mu*(E.A1 + mu*E.A2);
      const float den = E.c0 + mu*(E.c1 + mu*(E.c2 + mu*(E.c3 + mu*16.f)));
      const float f = wred(num/den);
      if (lane == 0) r8[nwv][q] = f;
    }
    __syncthreads();
    if (threadIdx.x < nc){
      float s = 0.f;
      #pragma unroll
      for (int w = 0; w < 8; ++w) s += r8[w][threadIdx.x];
      pr[(round & 1)*2048 + blockIdx.x*8 + threadIdx.x] = s;
    }
    gg.sync();
    // redundant global reduce (identical tree in every block)
    for (int q = 0; q < nc; ++q){
      float v = 0.f;
      if (threadIdx.x < 256) v = pr[(round & 1)*2048 + threadIdx.x*8 + q];
      v = wred(v);
      if (lane == 0) r8[nwv][q] = v;
    }
    __syncthreads();
    float tot[7];
    for (int q = 0; q < nc; ++q){
      float s = 0.f;
      #pragma unroll
      for (int w = 0; w < 8; ++w) s += r8[w][q];
      tot[q] = s;
    }
    __syncthreads();
    // walk decisions (exact same f32 midpoints as sequential bisection)
    if (nc == 7){
      const bool b1 = tot[0] > 1.0f;
      const float l1 = b1 ? c[0] : lo, h1 = b1 ? hi : c[0];
      const int  q2 = b1 ? 2 : 1;
      const bool b2 = tot[q2] > 1.0f;
      const float l2 = b2 ? c[q2] : l1, h2 = b2 ? h1 : c[q2];
      const int  q3 = 3 + (b1 ? 2 : 0) + (b2 ? 1 : 0);
      const bool b3 = tot[q3] > 1.0f;
      lo = b3 ? c[q3] : l2; hi = b3 ? h2 : c[q3];
    } else {
      const bool b1 = tot[0] > 1.0f;
      lo = b1 ? c[0] : lo; hi = b1 ? hi : c[0];
    }
  }

  // final mu (20th midpoint), V and Pm
  const float mu = 0.5f*(lo + hi);
  C2 det; det.x = E.d0.x + mu*E.d1.x + 4.f*mu*mu; det.y = E.d0.y + mu*E.d1.y;
  const float id = 1.f/cabs2(det);
  C2 idet; idet.x = det.x*id; idet.y = -det.y*id;
  C2 Vv[2][2];
  #pragma unroll
  for (int k = 0; k < 2; ++k)
    #pragma unroll
    for (int i = 0; i < 2; ++i){
      C2 t; t.x = E.p[k][i].x + 2.f*mu*E.g[k][i].x; t.y = E.p[k][i].y + 2.f*mu*E.g[k][i].y;
      Vv[i][k] = cmul(E.UW[k], cmul(t, idet));
    }
  *(float4*)(V + (size_t)gid*4)     = make_float4(Vv[0][0].x, Vv[0][0].y, Vv[0][1].x, Vv[0][1].y);
  *(float4*)(V + (size_t)gid*4 + 2) = make_float4(Vv[1][0].x, Vv[1][0].y, Vv[1][1].x, Vv[1][1].y);
  const float2 gg2 = g2[gid & 4095];
  C2 gc; gc.x = gg2.x; gc.y = gg2.y;
  float P = 0.f;
  #pragma unroll
  for (int k = 0; k < 2; ++k){
    const C2 a = Vv[0][k], b = Vv[1][k];
    P += cabs2(a) + cabs2(b);
    const C2 t = cmul(gc, cmul(a, conjc(b)));
    P += 2.f*t.x;
  }
  Pm[gid] = P;
}

// ---------------------------------------------------------------- output
__global__ void k_out(const float2* __restrict__ frf, const float2* __restrict__ V,
                      const float* __restrict__ Pm, float* __restrict__ out)
{
  const int b2 = blockIdx.x;
  const int t = threadIdx.x & 63;
  const int ng = threadIdx.x >> 6;
  const float4 f = *(const float4*)(frf + ((size_t)b2*64 + t)*2);
  C2 f0, f1; f0.x = f.x; f0.y = f.y; f1.x = f.z; f1.y = f.w;
  for (int n = ng; n < 32; n += 4){
    const float4* mv = (const float4*)(V + ((size_t)n*4096 + b2)*4);
    const float4 m0 = mv[0];
    const float4 m1 = mv[1];
    C2 M00, M01, M10, M11;
    M00.x = m0.x; M00.y = m0.y; M01.x = m0.z; M01.y = m0.w;
    M10.x = m1.x; M10.y = m1.y; M11.x = m1.z; M11.y = m1.w;
    const float sc = 1.41421356237f * rsqrtf(Pm[b2*32 + n]);
    const C2 c0 = cadd(cmul(f0, M00), cmul(f1, M10));
    const C2 c1 = cadd(cmul(f0, M01), cmul(f1, M11));
    const size_t base = (size_t)b2*8192 + n*128 + t*2;
    *(float2*)(out + base)        = make_float2(c0.x*sc, c1.x*sc);
    *(float2*)(out + base + 4096) = make_float2(c0.y*sc, c1.y*sc);
  }
}

// ---------------------------------------------------------------- launch
extern "C" void kernel_launch(void* const* d_in, const int* in_sizes, int n_in,
                              void* d_out, int out_size, void* d_ws, size_t ws_size,
                              hipStream_t stream)
{
  const float* H  = (const float*)d_in[0];
  const float* W0 = (const float*)d_in[1];
  const float* b0 = (const float*)d_in[2];
  const float* W1 = (const float*)d_in[3];
  const float* b1 = (const float*)d_in[4];
  const float* W2 = (const float*)d_in[5];
  const float* b2 = (const float*)d_in[6];
  const float* W3 = (const float*)d_in[7];
  const float* b3 = (const float*)d_in[8];
  float* out = (float*)d_out;
  char* ws = (char*)d_ws;
  (void)in_sizes; (void)n_in; (void)out_size; (void)ws_size;

  size_t o = 0;
  auto alloc = [&](size_t bytes) -> void* {
    void* p = ws + o;
    o += (bytes + 255) & ~(size_t)255;
    return p;
  };
  float2* frf   = (float2*)alloc((size_t)4096*64*2*sizeof(float2)); // 4 MiB
  float2* g2    = (float2*)alloc((size_t)4096*sizeof(float2));
  float*  xbuf  = (float*) alloc((size_t)M2N*8*sizeof(float));      // 4 MiB
  float*  ybuf  = (float*) alloc((size_t)M2N*8*sizeof(float));      // 4 MiB
  float2* V     = (float2*)alloc((size_t)M2N*4*sizeof(float2));     // 4 MiB
  float*  Pm    = (float*) alloc((size_t)M2N*sizeof(float));        // 0.5 MiB
  float*  pr    = (float*) alloc((size_t)2*2048*sizeof(float));     // 16 KiB
  f16*    wfr12 = (f16*)   alloc((size_t)256*1024*sizeof(f16));     // 512 KiB
  f16*    wfr0  = (f16*)   alloc((size_t)16*1024*sizeof(f16));      // 32 KiB
  f16*    wfr3  = (f16*)   alloc((size_t)8*1024*sizeof(f16));       // 16 KiB

  k_prep<<<66, 256, 0, stream>>>(W0, W1, W2, W3, wfr12, wfr0, wfr3);
  k_frf<<<2048, 256, 0, stream>>>(H, frf, g2);
  k_hequ<<<32768, 256, 0, stream>>>(H, frf, xbuf);
  k_mlp<<<2048, 256, 0, stream>>>(xbuf, wfr12, wfr0, wfr3, b0, b1, b2, b3, ybuf);
  {
    void* kargs[] = { (void*)&xbuf, (void*)&ybuf, (void*)&g2, (void*)&pr,
                      (void*)&V, (void*)&Pm };
    hipLaunchCooperativeKernel((void*)k_solve, dim3(256), dim3(512), kargs, 0, stream);
  }
  k_out<<<4096, 256, 0, stream>>>(frf, V, Pm, out);
}

// Round 4
// 397.067 us; speedup vs baseline: 1.1681x; 1.1207x over previous
//
#include <hip/hip_runtime.h>

typedef _Float16 f16;
typedef __attribute__((ext_vector_type(8))) _Float16 f16x8;
typedef __attribute__((ext_vector_type(4))) float f32x4;
typedef unsigned int u32;

#define M2N 131072   // BATCH(4096) * Nc(32)
#define MFMA16 __builtin_amdgcn_mfma_f32_16x16x32_f16

struct C2 { float x, y; };
__device__ __forceinline__ C2 cmul(C2 a, C2 b){ C2 r; r.x = a.x*b.x - a.y*b.y; r.y = a.x*b.y + a.y*b.x; return r; }
__device__ __forceinline__ C2 cadd(C2 a, C2 b){ C2 r; r.x = a.x+b.x; r.y = a.y+b.y; return r; }
__device__ __forceinline__ C2 csub(C2 a, C2 b){ C2 r; r.x = a.x-b.x; r.y = a.y-b.y; return r; }
__device__ __forceinline__ C2 conjc(C2 a){ C2 r; r.x = a.x; r.y = -a.y; return r; }
__device__ __forceinline__ C2 cneg(C2 a){ C2 r; r.x = -a.x; r.y = -a.y; return r; }
__device__ __forceinline__ float cabs2(C2 a){ return a.x*a.x + a.y*a.y; }
__device__ __forceinline__ float dotr(C2 a, C2 b){ return a.x*b.x + a.y*b.y; }

__device__ __forceinline__ float wred(float v){
  #pragma unroll
  for (int s = 32; s > 0; s >>= 1) v += __shfl_xor(v, s, 64);
  return v;
}

// Custom grid barrier: arrive-count + generation, agent scope. ~2-4 us vs
// ~30 us for cg::grid_group::sync() (sleep-backoff). Requires co-resident
// blocks (cooperative launch). bar[0]=count, bar[1]=gen; zeroed by k_prep.
__device__ __forceinline__ void gbarrier(int* bar, int nb){
  __syncthreads();
  if (threadIdx.x == 0){
    const int g = __hip_atomic_load(bar + 1, __ATOMIC_RELAXED, __HIP_MEMORY_SCOPE_AGENT);
    const int a = __hip_atomic_fetch_add(bar, 1, __ATOMIC_ACQ_REL, __HIP_MEMORY_SCOPE_AGENT);
    if (a == nb - 1){
      __hip_atomic_store(bar, 0, __ATOMIC_RELAXED, __HIP_MEMORY_SCOPE_AGENT);
      __hip_atomic_store(bar + 1, g + 1, __ATOMIC_RELEASE, __HIP_MEMORY_SCOPE_AGENT);
    } else {
      while (__hip_atomic_load(bar + 1, __ATOMIC_ACQUIRE, __HIP_MEMORY_SCOPE_AGENT) == g)
        __builtin_amdgcn_s_sleep(1);
    }
  }
  __syncthreads();
}

// ---------------------------------------------------------------- prep
// Build frag-linear hi/lo f16 weight fragments for 16x16x32 MFMA.
// B-frag: lane l holds B[k = kt*32 + (l>>4)*8 + e][n = nt*16 + (l&15)].
// wfr12: [L(2)][nt(16)][kt(8)] x [hi 512 f16][lo 512 f16]
// wfr0 : [nt(16)] x [hi 512][lo 512]   (K=32 padded, real k<8)
// wfr3 : [kt(8)]  x [hi 512][lo 512]   (N=16 padded, real n<8)
__global__ void k_prep(const float* __restrict__ W0, const float* __restrict__ W1,
                       const float* __restrict__ W2, const float* __restrict__ W3,
                       f16* __restrict__ wfr12, f16* __restrict__ wfr0,
                       f16* __restrict__ wfr3, int* __restrict__ bar)
{
  const int b = blockIdx.x, tid = threadIdx.x;
  if (b < 64){
    const int slot = b*256 + tid;        // [0, 16384)
    const int lane = slot & 63;
    const int rest = slot >> 6;          // L*128 + nt*8 + kt
    const int kt = rest & 7, nt = (rest >> 3) & 15, L = rest >> 7;
    const float* W = L ? W2 : W1;
    const int n = nt*16 + (lane & 15);
    f16* dst = wfr12 + (size_t)rest*1024 + lane*8;
    #pragma unroll
    for (int e = 0; e < 8; ++e){
      const int k = kt*32 + (lane>>4)*8 + e;
      const float w = W[k*256 + n];
      const f16 h = (f16)w;
      dst[e] = h; dst[512+e] = (f16)(w - (float)h);
    }
  } else if (b == 64){
    for (int i = 0; i < 4; ++i){
      const int slot = i*256 + tid;      // [0,1024)
      const int lane = slot & 63, nt = slot >> 6;
      const int col = nt*16 + (lane & 15);
      f16* dst = wfr0 + (size_t)nt*1024 + lane*8;
      #pragma unroll
      for (int e = 0; e < 8; ++e){
        const int k = (lane>>4)*8 + e;
        const float w = (k < 8) ? W0[k*256 + col] : 0.f;
        const f16 h = (f16)w;
        dst[e] = h; dst[512+e] = (f16)(w - (float)h);
      }
    }
  } else {
    if (tid < 8){
      __hip_atomic_store(bar + tid, 0, __ATOMIC_RELAXED, __HIP_MEMORY_SCOPE_AGENT);
    }
    for (int i = 0; i < 2; ++i){
      const int slot = i*256 + tid;      // [0,512)
      const int lane = slot & 63, kt = slot >> 6;
      const int col = lane & 15;
      f16* dst = wfr3 + (size_t)kt*1024 + lane*8;
      #pragma unroll
      for (int e = 0; e < 8; ++e){
        const int k = kt*32 + (lane>>4)*8 + e;
        const float w = (col < 8) ? W3[k*8 + col] : 0.f;
        const f16 h = (f16)w;
        dst[e] = h; dst[512+e] = (f16)(w - (float)h);
      }
    }
  }
}

// ---------------------------------------------------------------- F_RF + g2
__global__ void k_frf(const float* __restrict__ H, float2* __restrict__ frf,
                      float2* __restrict__ g2)
{
  const int b2 = blockIdx.x*2 + (threadIdx.x >> 7);
  const int tt = threadIdx.x & 127;
  const int t = tt >> 1, k = tt & 1;
  __shared__ float2 s[2][128];
  const size_t base = ((size_t)(b2*2 + k)*32 + 16)*128;
  const float are = H[base + t];
  const float aim = H[base];
  const float inv = rsqrtf(are*are + aim*aim) * 0.125f;
  float2 v; v.x = are*inv; v.y = -aim*inv;
  frf[((size_t)b2*64 + t)*2 + k] = v;
  s[threadIdx.x >> 7][tt] = v;
  __syncthreads();
  const int w = threadIdx.x >> 6;
  if ((w & 1) == 0){
    const int half = w >> 1;
    const int lane = threadIdx.x & 63;
    const float2 a = s[half][lane*2];
    const float2 b = s[half][lane*2 + 1];
    float re = a.x*b.x + a.y*b.y;          // a * conj(b)
    float im = a.y*b.x - a.x*b.y;
    re = wred(re); im = wred(im);
    if (lane == 0){ float2 g; g.x = re; g.y = im; g2[blockIdx.x*2 + half] = g; }
  }
}

// ---------------------------------------------------------------- H_equ -> x
__global__ void k_hequ(const float* __restrict__ H, const float2* __restrict__ frf,
                       float* __restrict__ x)
{
  const int m2 = blockIdx.x*4 + (threadIdx.x >> 6);
  const int lane = threadIdx.x & 63;
  const int n = m2 >> 12, b2 = m2 & 4095;
  const float4 f = *(const float4*)(frf + ((size_t)b2*64 + lane)*2);
  float accr[2][2], acci[2][2];
  #pragma unroll
  for (int i = 0; i < 2; ++i){
    const float* hr = H + (size_t)(n*8192 + b2*2 + i) * 128;
    const float re = hr[lane];
    const float im = hr[0];
    accr[i][0] = re*f.x - im*f.y;  acci[i][0] = re*f.y + im*f.x;
    accr[i][1] = re*f.z - im*f.w;  acci[i][1] = re*f.w + im*f.z;
  }
  #pragma unroll
  for (int i = 0; i < 2; ++i)
    #pragma unroll
    for (int j = 0; j < 2; ++j){ accr[i][j] = wred(accr[i][j]); acci[i][j] = wred(acci[i][j]); }
  if (lane == 0){
    float pw = 0.f;
    #pragma unroll
    for (int i = 0; i < 2; ++i)
      #pragma unroll
      for (int j = 0; j < 2; ++j) pw += accr[i][j]*accr[i][j] + acci[i][j]*acci[i][j];
    const float rs = rsqrtf(pw);
    *(float4*)(x + (size_t)m2*8)     = make_float4(accr[0][0]*rs, accr[0][1]*rs, accr[1][0]*rs, accr[1][1]*rs);
    *(float4*)(x + (size_t)m2*8 + 4) = make_float4(acci[0][0]*rs, acci[0][1]*rs, acci[1][0]*rs, acci[1][1]*rs);
  }
}

// ---------------------------------------------------------------- fused MLP
__device__ __forceinline__ void unpack8(uint4 q0, uint4 q1, f16x8& ah, f16x8& al){
  union UU { uint4 u; f16x8 f; } Hh, Ll;
  Hh.u.x = __builtin_amdgcn_perm(q0.y, q0.x, 0x05040100u);
  Hh.u.y = __builtin_amdgcn_perm(q0.w, q0.z, 0x05040100u);
  Hh.u.z = __builtin_amdgcn_perm(q1.y, q1.x, 0x05040100u);
  Hh.u.w = __builtin_amdgcn_perm(q1.w, q1.z, 0x05040100u);
  Ll.u.x = __builtin_amdgcn_perm(q0.y, q0.x, 0x07060302u);
  Ll.u.y = __builtin_amdgcn_perm(q0.w, q0.z, 0x07060302u);
  Ll.u.z = __builtin_amdgcn_perm(q1.y, q1.x, 0x07060302u);
  Ll.u.w = __builtin_amdgcn_perm(q1.w, q1.z, 0x07060302u);
  ah = Hh.f; al = Ll.f;
}

__launch_bounds__(256, 2)
__global__ void k_mlp(const float* __restrict__ x, const f16* __restrict__ wfr12,
                      const f16* __restrict__ wfr0, const f16* __restrict__ wfr3,
                      const float* __restrict__ bias0, const float* __restrict__ bias1,
                      const float* __restrict__ bias2, const float* __restrict__ bias3,
                      float* __restrict__ y)
{
  __shared__ u32 xa[64*256];   // 64 KiB -> 2 blocks/CU
  const int tid = threadIdx.x, blk = blockIdx.x;
  const int lane = tid & 63, wv = tid >> 6;
  const int l15 = lane & 15, lh = lane >> 4;

  f32x4 acc[4][4];
  f16x8 ah[4], al[4], bh[4], bl[4];

  auto EPI = [&](){   // relu + exact f16 split + pack + swizzled LDS write
    #pragma unroll
    for (int Mt = 0; Mt < 4; ++Mt)
      #pragma unroll
      for (int nt = 0; nt < 4; ++nt)
        #pragma unroll
        for (int r = 0; r < 4; ++r){
          const float v = fmaxf(acc[Mt][nt][r], 0.f);
          const f16 h = (f16)v;
          const f16 lo16 = (f16)(v - (float)h);
          const u32 p = (u32)__builtin_bit_cast(unsigned short, h)
                      | ((u32)__builtin_bit_cast(unsigned short, lo16) << 16);
          const int row = Mt*16 + lh*4 + r;
          const int col = wv*64 + nt*16 + l15;
          xa[row*256 + (col ^ ((row&7)<<2))] = p;
        }
  };

  // ---------- layer 0 (8 -> 256, K padded to 32; zero-padded B kills garbage A)
  #pragma unroll
  for (int nt = 0; nt < 4; ++nt){
    const float bb = bias0[wv*64 + nt*16 + l15];
    f32x4 v = {bb,bb,bb,bb};
    #pragma unroll
    for (int Mt = 0; Mt < 4; ++Mt) acc[Mt][nt] = v;
  }
  #pragma unroll
  for (int Mt = 0; Mt < 4; ++Mt){
    const float* xr = x + ((size_t)blk*64 + Mt*16 + l15)*8;
    const float4 v0 = *(const float4*)xr;
    const float4 v1 = *(const float4*)(xr+4);
    const float vv[8] = {v0.x,v0.y,v0.z,v0.w,v1.x,v1.y,v1.z,v1.w};
    #pragma unroll
    for (int e = 0; e < 8; ++e){
      const f16 h = (f16)vv[e];
      ah[Mt][e] = h; al[Mt][e] = (f16)(vv[e] - (float)h);
    }
  }
  #pragma unroll
  for (int nt = 0; nt < 4; ++nt){
    bh[nt] = *(const f16x8*)(wfr0 + (size_t)(wv*4+nt)*1024 + lane*8);
    bl[nt] = *(const f16x8*)(wfr0 + (size_t)(wv*4+nt)*1024 + 512 + lane*8);
  }
  #pragma unroll
  for (int Mt = 0; Mt < 4; ++Mt)
    #pragma unroll
    for (int nt = 0; nt < 4; ++nt){
      acc[Mt][nt] = MFMA16(ah[Mt], bh[nt], acc[Mt][nt], 0, 0, 0);
      acc[Mt][nt] = MFMA16(al[Mt], bh[nt], acc[Mt][nt], 0, 0, 0);
      acc[Mt][nt] = MFMA16(ah[Mt], bl[nt], acc[Mt][nt], 0, 0, 0);
    }
  EPI();
  __syncthreads();

  // ---------- layers 1,2 (256 -> 256)
  for (int L = 0; L < 2; ++L){
    const float* bs = L ? bias2 : bias1;
    #pragma unroll
    for (int nt = 0; nt < 4; ++nt){
      const float bb = bs[wv*64 + nt*16 + l15];
      f32x4 v = {bb,bb,bb,bb};
      #pragma unroll
      for (int Mt = 0; Mt < 4; ++Mt) acc[Mt][nt] = v;
    }
    #pragma unroll 1
    for (int kt = 0; kt < 8; ++kt){
      #pragma unroll
      for (int Mt = 0; Mt < 4; ++Mt){
        const int row = Mt*16 + l15;
        const int cb = kt*32 + lh*8;
        const int sw = (row&7)<<2;
        const uint4 q0 = *(const uint4*)(xa + row*256 + (cb ^ sw));
        const uint4 q1 = *(const uint4*)(xa + row*256 + ((cb+4) ^ sw));
        unpack8(q0, q1, ah[Mt], al[Mt]);
      }
      #pragma unroll
      for (int nt = 0; nt < 4; ++nt){
        const size_t f = ((size_t)(L*128 + (wv*4+nt)*8 + kt))*1024;
        bh[nt] = *(const f16x8*)(wfr12 + f + lane*8);
        bl[nt] = *(const f16x8*)(wfr12 + f + 512 + lane*8);
      }
      #pragma unroll
      for (int Mt = 0; Mt < 4; ++Mt)
        #pragma unroll
        for (int nt = 0; nt < 4; ++nt){
          acc[Mt][nt] = MFMA16(ah[Mt], bh[nt], acc[Mt][nt], 0, 0, 0);
          acc[Mt][nt] = MFMA16(al[Mt], bh[nt], acc[Mt][nt], 0, 0, 0);
          acc[Mt][nt] = MFMA16(ah[Mt], bl[nt], acc[Mt][nt], 0, 0, 0);
        }
    }
    __syncthreads();   // all reads done before overwrite
    EPI();
    __syncthreads();
  }

  // ---------- layer 3 (256 -> 8, N padded to 16; zero-padded B cols)
  f32x4 a3[4];
  {
    const float bb = (l15 < 8) ? bias3[l15] : 0.f;
    f32x4 v = {bb,bb,bb,bb};
    #pragma unroll
    for (int Mt = 0; Mt < 4; ++Mt) a3[Mt] = v;
  }
  #pragma unroll 1
  for (int kt = 0; kt < 8; ++kt){
    #pragma unroll
    for (int Mt = 0; Mt < 4; ++Mt){
      const int row = Mt*16 + l15;
      const int cb = kt*32 + lh*8;
      const int sw = (row&7)<<2;
      const uint4 q0 = *(const uint4*)(xa + row*256 + (cb ^ sw));
      const uint4 q1 = *(const uint4*)(xa + row*256 + ((cb+4) ^ sw));
      unpack8(q0, q1, ah[Mt], al[Mt]);
    }
    const f16x8 b3h = *(const f16x8*)(wfr3 + (size_t)kt*1024 + lane*8);
    const f16x8 b3l = *(const f16x8*)(wfr3 + (size_t)kt*1024 + 512 + lane*8);
    #pragma unroll
    for (int Mt = 0; Mt < 4; ++Mt){
      a3[Mt] = MFMA16(ah[Mt], b3h, a3[Mt], 0, 0, 0);
      a3[Mt] = MFMA16(al[Mt], b3h, a3[Mt], 0, 0, 0);
      a3[Mt] = MFMA16(ah[Mt], b3l, a3[Mt], 0, 0, 0);
    }
  }
  if (l15 < 8){
    #pragma unroll
    for (int Mt = 0; Mt < 4; ++Mt)
      #pragma unroll
      for (int r = 0; r < 4; ++r)
        y[((size_t)blk*64 + Mt*16 + lh*4 + r)*8 + l15] = a3[Mt][r];
  }
}

// ---------------------------------------------------------------- per-element algebra
struct Elem {
  C2 p[2][2], g[2][2], UW[2], d0, d1;
  float A0, A1, A2, c0, c1, c2, c3;
};

__device__ __forceinline__ void elem_core(const float* __restrict__ x,
                                          const float* __restrict__ y,
                                          int gid, Elem& E)
{
  const float4 xr = *(const float4*)(x + (size_t)gid*8);
  const float4 xi = *(const float4*)(x + (size_t)gid*8 + 4);
  C2 h[2][2];
  h[0][0].x = xr.x; h[0][0].y = xi.x; h[0][1].x = xr.y; h[0][1].y = xi.y;
  h[1][0].x = xr.z; h[1][0].y = xi.z; h[1][1].x = xr.w; h[1][1].y = xi.w;
  const float4 ya = *(const float4*)(y + (size_t)gid*8);
  const float4 yb = *(const float4*)(y + (size_t)gid*8 + 4);
  C2 U[2], Wm[2];
  U[0].x = ya.x; U[0].y = ya.z;  U[1].x = ya.y; U[1].y = ya.w;
  Wm[0].x = yb.x; Wm[0].y = yb.z; Wm[1].x = yb.y; Wm[1].y = yb.w;
  const float u20 = cabs2(U[0]), u21 = cabs2(U[1]);
  C2 cf[2];
  cf[0].x = Wm[0].x*u20; cf[0].y = Wm[0].y*u20;
  cf[1].x = Wm[1].x*u21; cf[1].y = Wm[1].y*u21;
  C2 B[2][2];
  #pragma unroll
  for (int i = 0; i < 2; ++i)
    #pragma unroll
    for (int j = 0; j < 2; ++j){
      const C2 t0 = cmul(conjc(h[0][i]), h[0][j]);
      const C2 t1 = cmul(conjc(h[1][i]), h[1][j]);
      B[i][j] = cadd(cmul(cf[0], t0), cmul(cf[1], t1));
    }
  C2 adj[2][2];
  adj[0][0] = B[1][1]; adj[0][1] = cneg(B[0][1]);
  adj[1][0] = cneg(B[1][0]); adj[1][1] = B[0][0];
  E.d0 = csub(cmul(B[0][0], B[1][1]), cmul(B[0][1], B[1][0]));
  E.d1.x = 2.f*(B[0][0].x + B[1][1].x);
  E.d1.y = 2.f*(B[0][0].y + B[1][1].y);
  #pragma unroll
  for (int k = 0; k < 2; ++k){
    #pragma unroll
    for (int j = 0; j < 2; ++j) E.g[k][j] = conjc(h[k][j]);
    #pragma unroll
    for (int i = 0; i < 2; ++i)
      E.p[k][i] = cadd(cmul(adj[i][0], E.g[k][0]), cmul(adj[i][1], E.g[k][1]));
    E.UW[k] = cmul(U[k], Wm[k]);
  }
  const float w0 = cabs2(E.UW[0]), w1 = cabs2(E.UW[1]);
  E.A0 = w0*(cabs2(E.p[0][0]) + cabs2(E.p[0][1])) + w1*(cabs2(E.p[1][0]) + cabs2(E.p[1][1]));
  E.A1 = 4.f*( w0*(dotr(E.p[0][0], E.g[0][0]) + dotr(E.p[0][1], E.g[0][1]))
             + w1*(dotr(E.p[1][0], E.g[1][0]) + dotr(E.p[1][1], E.g[1][1])) );
  E.A2 = 4.f*( w0*(cabs2(E.g[0][0]) + cabs2(E.g[0][1]))
             + w1*(cabs2(E.g[1][0]) + cabs2(E.g[1][1])) );
  E.c0 = cabs2(E.d0);
  E.c1 = 2.f*(E.d0.x*E.d1.x + E.d0.y*E.d1.y);
  E.c2 = cabs2(E.d1) + 8.f*E.d0.x;
  E.c3 = 8.f*E.d1.x;
}

// ---------------------------------------------------------------- fused bisection solve
// Cooperative launch (co-residency) + custom agent-scope barrier.
// 3 bisection levels per barrier (7 candidate mus = exact f32 midpoints of
// the decision tree), 7 barriers for 19 decisions. Double-buffered block
// partials; every block redundantly reduces all 256 partials identically.
__global__ void k_solve(const float* __restrict__ x, const float* __restrict__ y,
                        const float2* __restrict__ g2, float* __restrict__ pr,
                        int* __restrict__ bar, float2* __restrict__ V,
                        float* __restrict__ Pm)
{
  const int gid = blockIdx.x*512 + threadIdx.x;
  const int lane = threadIdx.x & 63, nwv = threadIdx.x >> 6;
  const int nblocks = gridDim.x;
  Elem E;
  elem_core(x, y, gid, E);
  __shared__ float r8[8][8];

  float lo = 0.f, hi = 10.f;
  for (int round = 0; round < 7; ++round){
    const int nc = (round < 6) ? 7 : 1;
    float c[7];
    const float m1 = 0.5f*(lo + hi);
    c[0] = m1;
    if (nc == 7){
      const float cl = 0.5f*(lo + m1), ch = 0.5f*(m1 + hi);
      c[1] = cl; c[2] = ch;
      c[3] = 0.5f*(lo + cl); c[4] = 0.5f*(cl + m1);
      c[5] = 0.5f*(m1 + ch); c[6] = 0.5f*(ch + hi);
    }
    // per-wave partial sums of f(mu_q)
    for (int q = 0; q < nc; ++q){
      const float mu = c[q];
      const float num = E.A0 + mu*(E.A1 + mu*E.A2);
      const float den = E.c0 + mu*(E.c1 + mu*(E.c2 + mu*(E.c3 + mu*16.f)));
      const float f = wred(num/den);
      if (lane == 0) r8[nwv][q] = f;
    }
    __syncthreads();
    if (threadIdx.x < nc){
      float s = 0.f;
      #pragma unroll
      for (int w = 0; w < 8; ++w) s += r8[w][threadIdx.x];
      pr[(round & 1)*2048 + blockIdx.x*8 + threadIdx.x] = s;
    }
    gbarrier(bar, nblocks);
    // redundant global reduce (identical tree in every block)
    for (int q = 0; q < nc; ++q){
      float v = 0.f;
      if (threadIdx.x < 256) v = pr[(round & 1)*2048 + threadIdx.x*8 + q];
      v = wred(v);
      if (lane == 0) r8[nwv][q] = v;
    }
    __syncthreads();
    float tot[7];
    for (int q = 0; q < nc; ++q){
      float s = 0.f;
      #pragma unroll
      for (int w = 0; w < 8; ++w) s += r8[w][q];
      tot[q] = s;
    }
    __syncthreads();
    // walk decisions (exact same f32 midpoints as sequential bisection)
    if (nc == 7){
      const bool b1 = tot[0] > 1.0f;
      const float l1 = b1 ? c[0] : lo, h1 = b1 ? hi : c[0];
      const int  q2 = b1 ? 2 : 1;
      const bool b2 = tot[q2] > 1.0f;
      const float l2 = b2 ? c[q2] : l1, h2 = b2 ? h1 : c[q2];
      const int  q3 = 3 + (b1 ? 2 : 0) + (b2 ? 1 : 0);
      const bool b3 = tot[q3] > 1.0f;
      lo = b3 ? c[q3] : l2; hi = b3 ? h2 : c[q3];
    } else {
      const bool b1 = tot[0] > 1.0f;
      lo = b1 ? c[0] : lo; hi = b1 ? hi : c[0];
    }
  }

  // final mu (20th midpoint), V and Pm
  const float mu = 0.5f*(lo + hi);
  C2 det; det.x = E.d0.x + mu*E.d1.x + 4.f*mu*mu; det.y = E.d0.y + mu*E.d1.y;
  const float id = 1.f/cabs2(det);
  C2 idet; idet.x = det.x*id; idet.y = -det.y*id;
  C2 Vv[2][2];
  #pragma unroll
  for (int k = 0; k < 2; ++k)
    #pragma unroll
    for (int i = 0; i < 2; ++i){
      C2 t; t.x = E.p[k][i].x + 2.f*mu*E.g[k][i].x; t.y = E.p[k][i].y + 2.f*mu*E.g[k][i].y;
      Vv[i][k] = cmul(E.UW[k], cmul(t, idet));
    }
  *(float4*)(V + (size_t)gid*4)     = make_float4(Vv[0][0].x, Vv[0][0].y, Vv[0][1].x, Vv[0][1].y);
  *(float4*)(V + (size_t)gid*4 + 2) = make_float4(Vv[1][0].x, Vv[1][0].y, Vv[1][1].x, Vv[1][1].y);
  const float2 gg2 = g2[gid & 4095];
  C2 gc; gc.x = gg2.x; gc.y = gg2.y;
  float P = 0.f;
  #pragma unroll
  for (int k = 0; k < 2; ++k){
    const C2 a = Vv[0][k], b = Vv[1][k];
    P += cabs2(a) + cabs2(b);
    const C2 t = cmul(gc, cmul(a, conjc(b)));
    P += 2.f*t.x;
  }
  Pm[gid] = P;
}

// ---------------------------------------------------------------- output
__global__ void k_out(const float2* __restrict__ frf, const float2* __restrict__ V,
                      const float* __restrict__ Pm, float* __restrict__ out)
{
  const int b2 = blockIdx.x;
  const int t = threadIdx.x & 63;
  const int ng = threadIdx.x >> 6;
  const float4 f = *(const float4*)(frf + ((size_t)b2*64 + t)*2);
  C2 f0, f1; f0.x = f.x; f0.y = f.y; f1.x = f.z; f1.y = f.w;
  for (int n = ng; n < 32; n += 4){
    const float4* mv = (const float4*)(V + ((size_t)n*4096 + b2)*4);
    const float4 m0 = mv[0];
    const float4 m1 = mv[1];
    C2 M00, M01, M10, M11;
    M00.x = m0.x; M00.y = m0.y; M01.x = m0.z; M01.y = m0.w;
    M10.x = m1.x; M10.y = m1.y; M11.x = m1.z; M11.y = m1.w;
    const float sc = 1.41421356237f * rsqrtf(Pm[b2*32 + n]);
    const C2 c0 = cadd(cmul(f0, M00), cmul(f1, M10));
    const C2 c1 = cadd(cmul(f0, M01), cmul(f1, M11));
    const size_t base = (size_t)b2*8192 + n*128 + t*2;
    *(float2*)(out + base)        = make_float2(c0.x*sc, c1.x*sc);
    *(float2*)(out + base + 4096) = make_float2(c0.y*sc, c1.y*sc);
  }
}

// ---------------------------------------------------------------- launch
extern "C" void kernel_launch(void* const* d_in, const int* in_sizes, int n_in,
                              void* d_out, int out_size, void* d_ws, size_t ws_size,
                              hipStream_t stream)
{
  const float* H  = (const float*)d_in[0];
  const float* W0 = (const float*)d_in[1];
  const float* b0 = (const float*)d_in[2];
  const float* W1 = (const float*)d_in[3];
  const float* b1 = (const float*)d_in[4];
  const float* W2 = (const float*)d_in[5];
  const float* b2 = (const float*)d_in[6];
  const float* W3 = (const float*)d_in[7];
  const float* b3 = (const float*)d_in[8];
  float* out = (float*)d_out;
  char* ws = (char*)d_ws;
  (void)in_sizes; (void)n_in; (void)out_size; (void)ws_size;

  size_t o = 0;
  auto alloc = [&](size_t bytes) -> void* {
    void* p = ws + o;
    o += (bytes + 255) & ~(size_t)255;
    return p;
  };
  float2* frf   = (float2*)alloc((size_t)4096*64*2*sizeof(float2)); // 4 MiB
  float2* g2    = (float2*)alloc((size_t)4096*sizeof(float2));
  float*  xbuf  = (float*) alloc((size_t)M2N*8*sizeof(float));      // 4 MiB
  float*  ybuf  = (float*) alloc((size_t)M2N*8*sizeof(float));      // 4 MiB
  float2* V     = (float2*)alloc((size_t)M2N*4*sizeof(float2));     // 4 MiB
  float*  Pm    = (float*) alloc((size_t)M2N*sizeof(float));        // 0.5 MiB
  float*  pr    = (float*) alloc((size_t)2*2048*sizeof(float));     // 16 KiB
  int*    bar   = (int*)   alloc(8*sizeof(int));
  f16*    wfr12 = (f16*)   alloc((size_t)256*1024*sizeof(f16));     // 512 KiB
  f16*    wfr0  = (f16*)   alloc((size_t)16*1024*sizeof(f16));      // 32 KiB
  f16*    wfr3  = (f16*)   alloc((size_t)8*1024*sizeof(f16));       // 16 KiB

  k_prep<<<66, 256, 0, stream>>>(W0, W1, W2, W3, wfr12, wfr0, wfr3, bar);
  k_frf<<<2048, 256, 0, stream>>>(H, frf, g2);
  k_hequ<<<32768, 256, 0, stream>>>(H, frf, xbuf);
  k_mlp<<<2048, 256, 0, stream>>>(xbuf, wfr12, wfr0, wfr3, b0, b1, b2, b3, ybuf);
  {
    void* kargs[] = { (void*)&xbuf, (void*)&ybuf, (void*)&g2, (void*)&pr,
                      (void*)&bar, (void*)&V, (void*)&Pm };
    hipLaunchCooperativeKernel((void*)k_solve, dim3(256), dim3(512), kargs, 0, stream);
  }
  k_out<<<4096, 256, 0, stream>>>(frf, V, Pm, out);
}

// Round 5
// 308.309 us; speedup vs baseline: 1.5043x; 1.2879x over previous
//
#include <hip/hip_runtime.h>

typedef _Float16 f16;
typedef __attribute__((ext_vector_type(8))) _Float16 f16x8;
typedef __attribute__((ext_vector_type(4))) float f32x4;
typedef unsigned int u32;

#define M2N 131072   // BATCH(4096) * Nc(32)
#define MFMA16 __builtin_amdgcn_mfma_f32_16x16x32_f16

struct C2 { float x, y; };
__device__ __forceinline__ C2 cmul(C2 a, C2 b){ C2 r; r.x = a.x*b.x - a.y*b.y; r.y = a.x*b.y + a.y*b.x; return r; }
__device__ __forceinline__ C2 cadd(C2 a, C2 b){ C2 r; r.x = a.x+b.x; r.y = a.y+b.y; return r; }
__device__ __forceinline__ C2 csub(C2 a, C2 b){ C2 r; r.x = a.x-b.x; r.y = a.y-b.y; return r; }
__device__ __forceinline__ C2 conjc(C2 a){ C2 r; r.x = a.x; r.y = -a.y; return r; }
__device__ __forceinline__ C2 cneg(C2 a){ C2 r; r.x = -a.x; r.y = -a.y; return r; }
__device__ __forceinline__ float cabs2(C2 a){ return a.x*a.x + a.y*a.y; }
__device__ __forceinline__ float dotr(C2 a, C2 b){ return a.x*b.x + a.y*b.y; }

__device__ __forceinline__ float wred(float v){
  #pragma unroll
  for (int s = 32; s > 0; s >>= 1) v += __shfl_xor(v, s, 64);
  return v;
}

// Custom grid barrier (cooperative launch => co-resident blocks).
// Relaxed polling + s_sleep(8) to avoid per-poll L2-invalidate traffic;
// one ACQUIRE load on exit. bar[0]=count, bar[1]=gen; zeroed by k_prep.
__device__ __forceinline__ void gbarrier(int* bar, int nb){
  __syncthreads();
  if (threadIdx.x == 0){
    const int g = __hip_atomic_load(bar + 1, __ATOMIC_RELAXED, __HIP_MEMORY_SCOPE_AGENT);
    const int a = __hip_atomic_fetch_add(bar, 1, __ATOMIC_ACQ_REL, __HIP_MEMORY_SCOPE_AGENT);
    if (a == nb - 1){
      __hip_atomic_store(bar, 0, __ATOMIC_RELAXED, __HIP_MEMORY_SCOPE_AGENT);
      __hip_atomic_store(bar + 1, g + 1, __ATOMIC_RELEASE, __HIP_MEMORY_SCOPE_AGENT);
    } else {
      while (__hip_atomic_load(bar + 1, __ATOMIC_RELAXED, __HIP_MEMORY_SCOPE_AGENT) == g)
        __builtin_amdgcn_s_sleep(8);
      (void)__hip_atomic_load(bar + 1, __ATOMIC_ACQUIRE, __HIP_MEMORY_SCOPE_AGENT);
    }
  }
  __syncthreads();
}

// ---------------------------------------------------------------- prep
// Build frag-linear hi/lo f16 weight fragments for 16x16x32 MFMA.
// B-frag: lane l holds B[k = kt*32 + (l>>4)*8 + e][n = nt*16 + (l&15)].
// wfr12: [L(2)][nt(16)][kt(8)] x [hi 512 f16][lo 512 f16]
// wfr0 : [nt(16)] x [hi 512][lo 512]   (K=32 padded, real k<8)
// wfr3 : [kt(8)]  x [hi 512][lo 512]   (N=16 padded, real n<8)
__global__ void k_prep(const float* __restrict__ W0, const float* __restrict__ W1,
                       const float* __restrict__ W2, const float* __restrict__ W3,
                       f16* __restrict__ wfr12, f16* __restrict__ wfr0,
                       f16* __restrict__ wfr3, int* __restrict__ bar)
{
  const int b = blockIdx.x, tid = threadIdx.x;
  if (b < 64){
    const int slot = b*256 + tid;        // [0, 16384)
    const int lane = slot & 63;
    const int rest = slot >> 6;          // L*128 + nt*8 + kt
    const int kt = rest & 7, nt = (rest >> 3) & 15, L = rest >> 7;
    const float* W = L ? W2 : W1;
    const int n = nt*16 + (lane & 15);
    f16* dst = wfr12 + (size_t)rest*1024 + lane*8;
    #pragma unroll
    for (int e = 0; e < 8; ++e){
      const int k = kt*32 + (lane>>4)*8 + e;
      const float w = W[k*256 + n];
      const f16 h = (f16)w;
      dst[e] = h; dst[512+e] = (f16)(w - (float)h);
    }
  } else if (b == 64){
    for (int i = 0; i < 4; ++i){
      const int slot = i*256 + tid;      // [0,1024)
      const int lane = slot & 63, nt = slot >> 6;
      const int col = nt*16 + (lane & 15);
      f16* dst = wfr0 + (size_t)nt*1024 + lane*8;
      #pragma unroll
      for (int e = 0; e < 8; ++e){
        const int k = (lane>>4)*8 + e;
        const float w = (k < 8) ? W0[k*256 + col] : 0.f;
        const f16 h = (f16)w;
        dst[e] = h; dst[512+e] = (f16)(w - (float)h);
      }
    }
  } else {
    if (tid < 8){
      __hip_atomic_store(bar + tid, 0, __ATOMIC_RELAXED, __HIP_MEMORY_SCOPE_AGENT);
    }
    for (int i = 0; i < 2; ++i){
      const int slot = i*256 + tid;      // [0,512)
      const int lane = slot & 63, kt = slot >> 6;
      const int col = lane & 15;
      f16* dst = wfr3 + (size_t)kt*1024 + lane*8;
      #pragma unroll
      for (int e = 0; e < 8; ++e){
        const int k = kt*32 + (lane>>4)*8 + e;
        const float w = (col < 8) ? W3[k*8 + col] : 0.f;
        const f16 h = (f16)w;
        dst[e] = h; dst[512+e] = (f16)(w - (float)h);
      }
    }
  }
}

// ---------------------------------------------------------------- F_RF + g2
__global__ void k_frf(const float* __restrict__ H, float2* __restrict__ frf,
                      float2* __restrict__ g2)
{
  const int b2 = blockIdx.x*2 + (threadIdx.x >> 7);
  const int tt = threadIdx.x & 127;
  const int t = tt >> 1, k = tt & 1;
  __shared__ float2 s[2][128];
  const size_t base = ((size_t)(b2*2 + k)*32 + 16)*128;
  const float are = H[base + t];
  const float aim = H[base];
  const float inv = rsqrtf(are*are + aim*aim) * 0.125f;
  float2 v; v.x = are*inv; v.y = -aim*inv;
  frf[((size_t)b2*64 + t)*2 + k] = v;
  s[threadIdx.x >> 7][tt] = v;
  __syncthreads();
  const int w = threadIdx.x >> 6;
  if ((w & 1) == 0){
    const int half = w >> 1;
    const int lane = threadIdx.x & 63;
    const float2 a = s[half][lane*2];
    const float2 b = s[half][lane*2 + 1];
    float re = a.x*b.x + a.y*b.y;          // a * conj(b)
    float im = a.y*b.x - a.x*b.y;
    re = wred(re); im = wred(im);
    if (lane == 0){ float2 g; g.x = re; g.y = im; g2[blockIdx.x*2 + half] = g; }
  }
}

// ---------------------------------------------------------------- H_equ -> x
__global__ void k_hequ(const float* __restrict__ H, const float2* __restrict__ frf,
                       float* __restrict__ x)
{
  const int m2 = blockIdx.x*4 + (threadIdx.x >> 6);
  const int lane = threadIdx.x & 63;
  const int n = m2 >> 12, b2 = m2 & 4095;
  const float4 f = *(const float4*)(frf + ((size_t)b2*64 + lane)*2);
  float accr[2][2], acci[2][2];
  #pragma unroll
  for (int i = 0; i < 2; ++i){
    const float* hr = H + (size_t)(n*8192 + b2*2 + i) * 128;
    const float re = hr[lane];
    const float im = hr[0];
    accr[i][0] = re*f.x - im*f.y;  acci[i][0] = re*f.y + im*f.x;
    accr[i][1] = re*f.z - im*f.w;  acci[i][1] = re*f.w + im*f.z;
  }
  #pragma unroll
  for (int i = 0; i < 2; ++i)
    #pragma unroll
    for (int j = 0; j < 2; ++j){ accr[i][j] = wred(accr[i][j]); acci[i][j] = wred(acci[i][j]); }
  if (lane == 0){
    float pw = 0.f;
    #pragma unroll
    for (int i = 0; i < 2; ++i)
      #pragma unroll
      for (int j = 0; j < 2; ++j) pw += accr[i][j]*accr[i][j] + acci[i][j]*acci[i][j];
    const float rs = rsqrtf(pw);
    *(float4*)(x + (size_t)m2*8)     = make_float4(accr[0][0]*rs, accr[0][1]*rs, accr[1][0]*rs, accr[1][1]*rs);
    *(float4*)(x + (size_t)m2*8 + 4) = make_float4(acci[0][0]*rs, acci[0][1]*rs, acci[1][0]*rs, acci[1][1]*rs);
  }
}

// ---------------------------------------------------------------- fused MLP
__device__ __forceinline__ void unpack8(uint4 q0, uint4 q1, f16x8& ah, f16x8& al){
  union UU { uint4 u; f16x8 f; } Hh, Ll;
  Hh.u.x = __builtin_amdgcn_perm(q0.y, q0.x, 0x05040100u);
  Hh.u.y = __builtin_amdgcn_perm(q0.w, q0.z, 0x05040100u);
  Hh.u.z = __builtin_amdgcn_perm(q1.y, q1.x, 0x05040100u);
  Hh.u.w = __builtin_amdgcn_perm(q1.w, q1.z, 0x05040100u);
  Ll.u.x = __builtin_amdgcn_perm(q0.y, q0.x, 0x07060302u);
  Ll.u.y = __builtin_amdgcn_perm(q0.w, q0.z, 0x07060302u);
  Ll.u.z = __builtin_amdgcn_perm(q1.y, q1.x, 0x07060302u);
  Ll.u.w = __builtin_amdgcn_perm(q1.w, q1.z, 0x07060302u);
  ah = Hh.f; al = Ll.f;
}

__launch_bounds__(256, 2)
__global__ void k_mlp(const float* __restrict__ x, const f16* __restrict__ wfr12,
                      const f16* __restrict__ wfr0, const f16* __restrict__ wfr3,
                      const float* __restrict__ bias0, const float* __restrict__ bias1,
                      const float* __restrict__ bias2, const float* __restrict__ bias3,
                      float* __restrict__ y)
{
  __shared__ u32 xa[64*256];   // 64 KiB -> 2 blocks/CU
  const int tid = threadIdx.x, blk = blockIdx.x;
  const int lane = tid & 63, wv = tid >> 6;
  const int l15 = lane & 15, lh = lane >> 4;

  f32x4 acc[4][4];
  f16x8 ah[4], al[4], bh[4], bl[4];

  auto EPI = [&](){   // relu + exact f16 split + pack + swizzled LDS write
    #pragma unroll
    for (int Mt = 0; Mt < 4; ++Mt)
      #pragma unroll
      for (int nt = 0; nt < 4; ++nt)
        #pragma unroll
        for (int r = 0; r < 4; ++r){
          const float v = fmaxf(acc[Mt][nt][r], 0.f);
          const f16 h = (f16)v;
          const f16 lo16 = (f16)(v - (float)h);
          const u32 p = (u32)__builtin_bit_cast(unsigned short, h)
                      | ((u32)__builtin_bit_cast(unsigned short, lo16) << 16);
          const int row = Mt*16 + lh*4 + r;
          const int col = wv*64 + nt*16 + l15;
          xa[row*256 + (col ^ ((row&7)<<2))] = p;
        }
  };

  // ---------- layer 0 (8 -> 256, K padded to 32; zero-padded B kills garbage A)
  #pragma unroll
  for (int nt = 0; nt < 4; ++nt){
    const float bb = bias0[wv*64 + nt*16 + l15];
    f32x4 v = {bb,bb,bb,bb};
    #pragma unroll
    for (int Mt = 0; Mt < 4; ++Mt) acc[Mt][nt] = v;
  }
  #pragma unroll
  for (int Mt = 0; Mt < 4; ++Mt){
    const float* xr = x + ((size_t)blk*64 + Mt*16 + l15)*8;
    const float4 v0 = *(const float4*)xr;
    const float4 v1 = *(const float4*)(xr+4);
    const float vv[8] = {v0.x,v0.y,v0.z,v0.w,v1.x,v1.y,v1.z,v1.w};
    #pragma unroll
    for (int e = 0; e < 8; ++e){
      const f16 h = (f16)vv[e];
      ah[Mt][e] = h; al[Mt][e] = (f16)(vv[e] - (float)h);
    }
  }
  #pragma unroll
  for (int nt = 0; nt < 4; ++nt){
    bh[nt] = *(const f16x8*)(wfr0 + (size_t)(wv*4+nt)*1024 + lane*8);
    bl[nt] = *(const f16x8*)(wfr0 + (size_t)(wv*4+nt)*1024 + 512 + lane*8);
  }
  #pragma unroll
  for (int Mt = 0; Mt < 4; ++Mt)
    #pragma unroll
    for (int nt = 0; nt < 4; ++nt){
      acc[Mt][nt] = MFMA16(ah[Mt], bh[nt], acc[Mt][nt], 0, 0, 0);
      acc[Mt][nt] = MFMA16(al[Mt], bh[nt], acc[Mt][nt], 0, 0, 0);
      acc[Mt][nt] = MFMA16(ah[Mt], bl[nt], acc[Mt][nt], 0, 0, 0);
    }
  EPI();
  __syncthreads();

  // ---------- layers 1,2 (256 -> 256)
  for (int L = 0; L < 2; ++L){
    const float* bs = L ? bias2 : bias1;
    #pragma unroll
    for (int nt = 0; nt < 4; ++nt){
      const float bb = bs[wv*64 + nt*16 + l15];
      f32x4 v = {bb,bb,bb,bb};
      #pragma unroll
      for (int Mt = 0; Mt < 4; ++Mt) acc[Mt][nt] = v;
    }
    #pragma unroll 1
    for (int kt = 0; kt < 8; ++kt){
      #pragma unroll
      for (int Mt = 0; Mt < 4; ++Mt){
        const int row = Mt*16 + l15;
        const int cb = kt*32 + lh*8;
        const int sw = (row&7)<<2;
        const uint4 q0 = *(const uint4*)(xa + row*256 + (cb ^ sw));
        const uint4 q1 = *(const uint4*)(xa + row*256 + ((cb+4) ^ sw));
        unpack8(q0, q1, ah[Mt], al[Mt]);
      }
      #pragma unroll
      for (int nt = 0; nt < 4; ++nt){
        const size_t f = ((size_t)(L*128 + (wv*4+nt)*8 + kt))*1024;
        bh[nt] = *(const f16x8*)(wfr12 + f + lane*8);
        bl[nt] = *(const f16x8*)(wfr12 + f + 512 + lane*8);
      }
      #pragma unroll
      for (int Mt = 0; Mt < 4; ++Mt)
        #pragma unroll
        for (int nt = 0; nt < 4; ++nt){
          acc[Mt][nt] = MFMA16(ah[Mt], bh[nt], acc[Mt][nt], 0, 0, 0);
          acc[Mt][nt] = MFMA16(al[Mt], bh[nt], acc[Mt][nt], 0, 0, 0);
          acc[Mt][nt] = MFMA16(ah[Mt], bl[nt], acc[Mt][nt], 0, 0, 0);
        }
    }
    __syncthreads();   // all reads done before overwrite
    EPI();
    __syncthreads();
  }

  // ---------- layer 3 (256 -> 8, N padded to 16; zero-padded B cols)
  f32x4 a3[4];
  {
    const float bb = (l15 < 8) ? bias3[l15] : 0.f;
    f32x4 v = {bb,bb,bb,bb};
    #pragma unroll
    for (int Mt = 0; Mt < 4; ++Mt) a3[Mt] = v;
  }
  #pragma unroll 1
  for (int kt = 0; kt < 8; ++kt){
    #pragma unroll
    for (int Mt = 0; Mt < 4; ++Mt){
      const int row = Mt*16 + l15;
      const int cb = kt*32 + lh*8;
      const int sw = (row&7)<<2;
      const uint4 q0 = *(const uint4*)(xa + row*256 + (cb ^ sw));
      const uint4 q1 = *(const uint4*)(xa + row*256 + ((cb+4) ^ sw));
      unpack8(q0, q1, ah[Mt], al[Mt]);
    }
    const f16x8 b3h = *(const f16x8*)(wfr3 + (size_t)kt*1024 + lane*8);
    const f16x8 b3l = *(const f16x8*)(wfr3 + (size_t)kt*1024 + 512 + lane*8);
    #pragma unroll
    for (int Mt = 0; Mt < 4; ++Mt){
      a3[Mt] = MFMA16(ah[Mt], b3h, a3[Mt], 0, 0, 0);
      a3[Mt] = MFMA16(al[Mt], b3h, a3[Mt], 0, 0, 0);
      a3[Mt] = MFMA16(ah[Mt], b3l, a3[Mt], 0, 0, 0);
    }
  }
  if (l15 < 8){
    #pragma unroll
    for (int Mt = 0; Mt < 4; ++Mt)
      #pragma unroll
      for (int r = 0; r < 4; ++r)
        y[((size_t)blk*64 + Mt*16 + lh*4 + r)*8 + l15] = a3[Mt][r];
  }
}

// ---------------------------------------------------------------- per-element algebra
struct Elem {
  C2 p[2][2], g[2][2], UW[2], d0, d1;
  float A0, A1, A2, c0, c1, c2, c3;
};
struct Coef { float A0, A1, A2, c0, c1, c2, c3; };

__device__ __forceinline__ void elem_core(const float* __restrict__ x,
                                          const float* __restrict__ y,
                                          int gid, Elem& E)
{
  const float4 xr = *(const float4*)(x + (size_t)gid*8);
  const float4 xi = *(const float4*)(x + (size_t)gid*8 + 4);
  C2 h[2][2];
  h[0][0].x = xr.x; h[0][0].y = xi.x; h[0][1].x = xr.y; h[0][1].y = xi.y;
  h[1][0].x = xr.z; h[1][0].y = xi.z; h[1][1].x = xr.w; h[1][1].y = xi.w;
  const float4 ya = *(const float4*)(y + (size_t)gid*8);
  const float4 yb = *(const float4*)(y + (size_t)gid*8 + 4);
  C2 U[2], Wm[2];
  U[0].x = ya.x; U[0].y = ya.z;  U[1].x = ya.y; U[1].y = ya.w;
  Wm[0].x = yb.x; Wm[0].y = yb.z; Wm[1].x = yb.y; Wm[1].y = yb.w;
  const float u20 = cabs2(U[0]), u21 = cabs2(U[1]);
  C2 cf[2];
  cf[0].x = Wm[0].x*u20; cf[0].y = Wm[0].y*u20;
  cf[1].x = Wm[1].x*u21; cf[1].y = Wm[1].y*u21;
  C2 B[2][2];
  #pragma unroll
  for (int i = 0; i < 2; ++i)
    #pragma unroll
    for (int j = 0; j < 2; ++j){
      const C2 t0 = cmul(conjc(h[0][i]), h[0][j]);
      const C2 t1 = cmul(conjc(h[1][i]), h[1][j]);
      B[i][j] = cadd(cmul(cf[0], t0), cmul(cf[1], t1));
    }
  C2 adj[2][2];
  adj[0][0] = B[1][1]; adj[0][1] = cneg(B[0][1]);
  adj[1][0] = cneg(B[1][0]); adj[1][1] = B[0][0];
  E.d0 = csub(cmul(B[0][0], B[1][1]), cmul(B[0][1], B[1][0]));
  E.d1.x = 2.f*(B[0][0].x + B[1][1].x);
  E.d1.y = 2.f*(B[0][0].y + B[1][1].y);
  #pragma unroll
  for (int k = 0; k < 2; ++k){
    #pragma unroll
    for (int j = 0; j < 2; ++j) E.g[k][j] = conjc(h[k][j]);
    #pragma unroll
    for (int i = 0; i < 2; ++i)
      E.p[k][i] = cadd(cmul(adj[i][0], E.g[k][0]), cmul(adj[i][1], E.g[k][1]));
    E.UW[k] = cmul(U[k], Wm[k]);
  }
  const float w0 = cabs2(E.UW[0]), w1 = cabs2(E.UW[1]);
  E.A0 = w0*(cabs2(E.p[0][0]) + cabs2(E.p[0][1])) + w1*(cabs2(E.p[1][0]) + cabs2(E.p[1][1]));
  E.A1 = 4.f*( w0*(dotr(E.p[0][0], E.g[0][0]) + dotr(E.p[0][1], E.g[0][1]))
             + w1*(dotr(E.p[1][0], E.g[1][0]) + dotr(E.p[1][1], E.g[1][1])) );
  E.A2 = 4.f*( w0*(cabs2(E.g[0][0]) + cabs2(E.g[0][1]))
             + w1*(cabs2(E.g[1][0]) + cabs2(E.g[1][1])) );
  E.c0 = cabs2(E.d0);
  E.c1 = 2.f*(E.d0.x*E.d1.x + E.d0.y*E.d1.y);
  E.c2 = cabs2(E.d1) + 8.f*E.d0.x;
  E.c3 = 8.f*E.d1.x;
}

__device__ __forceinline__ float evalf(float mu, const Coef& C){
  const float num = C.A0 + mu*(C.A1 + mu*C.A2);
  const float den = C.c0 + mu*(C.c1 + mu*(C.c2 + mu*(C.c3 + mu*16.f)));
  return num/den;
}

// One multi-level bisection round: evaluate the full depth-LV candidate
// subtree ((1<<LV)-1 mus, bit-exact sequential midpoints via heap recursion),
// one grid barrier, then walk LV decisions.
template<int LV>
__device__ __forceinline__ void bis_round(float& lo, float& hi,
                                          const Coef& C0, const Coef& C1,
                                          float* __restrict__ pr, int* __restrict__ bar,
                                          int buf, int blk, int nb,
                                          float (*r8)[32], float* tot)
{
  constexpr int NN = (1 << LV) - 1;
  const int tid = threadIdx.x;
  const int lane = tid & 63, wv = tid >> 6;

  float nl[NN], nh[NN], cn[NN];
  nl[0] = lo; nh[0] = hi;
  #pragma unroll
  for (int i = 0; i < NN; ++i){
    cn[i] = 0.5f*(nl[i] + nh[i]);
    if (2*i + 2 < NN){
      nl[2*i+1] = nl[i]; nh[2*i+1] = cn[i];
      nl[2*i+2] = cn[i]; nh[2*i+2] = nh[i];
    }
  }
  #pragma unroll
  for (int q = 0; q < NN; ++q){
    float f = evalf(cn[q], C0) + evalf(cn[q], C1);
    f = wred(f);
    if (lane == 0) r8[wv][q] = f;
  }
  __syncthreads();
  if (tid < NN){
    float s = 0.f;
    #pragma unroll
    for (int w = 0; w < 16; ++w) s += r8[w][tid];
    pr[buf*2048 + blk*32 + tid] = s;
  }
  gbarrier(bar, nb);
  {
    const int q = 2*(tid >> 6) + ((tid & 63) >> 5);
    const int lb = tid & 31;
    if (q < NN){
      float s = pr[buf*2048 + lb*32 + q] + pr[buf*2048 + (lb+32)*32 + q];
      #pragma unroll
      for (int s2 = 16; s2 > 0; s2 >>= 1) s += __shfl_xor(s, s2, 64);
      if (lb == 0) tot[q] = s;
    }
  }
  __syncthreads();
  int i = 0;
  #pragma unroll
  for (int d = 0; d < LV; ++d){
    const float mu = 0.5f*(lo + hi);     // == cn[i] bit-exactly
    const bool big = tot[i] > 1.0f;
    lo = big ? mu : lo;
    hi = big ? hi : mu;
    i = 2*i + 1 + (big ? 1 : 0);
  }
  __syncthreads();
}

__device__ __forceinline__ void final_v(const float* __restrict__ x,
                                        const float* __restrict__ y,
                                        const float2* __restrict__ g2,
                                        int gid, float mu,
                                        float2* __restrict__ V, float* __restrict__ Pm)
{
  Elem E;
  elem_core(x, y, gid, E);
  C2 det; det.x = E.d0.x + mu*E.d1.x + 4.f*mu*mu; det.y = E.d0.y + mu*E.d1.y;
  const float id = 1.f/cabs2(det);
  C2 idet; idet.x = det.x*id; idet.y = -det.y*id;
  C2 Vv[2][2];
  #pragma unroll
  for (int k = 0; k < 2; ++k)
    #pragma unroll
    for (int i = 0; i < 2; ++i){
      C2 t; t.x = E.p[k][i].x + 2.f*mu*E.g[k][i].x; t.y = E.p[k][i].y + 2.f*mu*E.g[k][i].y;
      Vv[i][k] = cmul(E.UW[k], cmul(t, idet));
    }
  *(float4*)(V + (size_t)gid*4)     = make_float4(Vv[0][0].x, Vv[0][0].y, Vv[0][1].x, Vv[0][1].y);
  *(float4*)(V + (size_t)gid*4 + 2) = make_float4(Vv[1][0].x, Vv[1][0].y, Vv[1][1].x, Vv[1][1].y);
  const float2 gg2 = g2[gid & 4095];
  C2 gc; gc.x = gg2.x; gc.y = gg2.y;
  float P = 0.f;
  #pragma unroll
  for (int k = 0; k < 2; ++k){
    const C2 a = Vv[0][k], b = Vv[1][k];
    P += cabs2(a) + cabs2(b);
    const C2 t = cmul(gc, cmul(a, conjc(b)));
    P += 2.f*t.x;
  }
  Pm[gid] = P;
}

// ---------------------------------------------------------------- fused bisection solve
// 64 blocks x 1024 thr (cooperative). 2 elements/thread; only the 7 rational
// coefficients live through bisection. 4 barriers: rounds of 5+5+5+4 levels.
__launch_bounds__(1024)
__global__ void k_solve(const float* __restrict__ x, const float* __restrict__ y,
                        const float2* __restrict__ g2, float* __restrict__ pr,
                        int* __restrict__ bar, float2* __restrict__ V,
                        float* __restrict__ Pm)
{
  const int tid = threadIdx.x, blk = blockIdx.x;
  const int nb = gridDim.x;
  const int e0 = blk*2048 + tid, e1 = e0 + 1024;
  __shared__ float r8[16][32];
  __shared__ float tot[32];

  Coef C0, C1;
  { Elem E; elem_core(x, y, e0, E);
    C0.A0=E.A0; C0.A1=E.A1; C0.A2=E.A2; C0.c0=E.c0; C0.c1=E.c1; C0.c2=E.c2; C0.c3=E.c3; }
  { Elem E; elem_core(x, y, e1, E);
    C1.A0=E.A0; C1.A1=E.A1; C1.A2=E.A2; C1.c0=E.c0; C1.c1=E.c1; C1.c2=E.c2; C1.c3=E.c3; }

  float lo = 0.f, hi = 10.f;
  bis_round<5>(lo, hi, C0, C1, pr, bar, 0, blk, nb, r8, tot);
  bis_round<5>(lo, hi, C0, C1, pr, bar, 1, blk, nb, r8, tot);
  bis_round<5>(lo, hi, C0, C1, pr, bar, 0, blk, nb, r8, tot);
  bis_round<4>(lo, hi, C0, C1, pr, bar, 1, blk, nb, r8, tot);

  const float mu = 0.5f*(lo + hi);   // 20th midpoint, as in reference
  final_v(x, y, g2, e0, mu, V, Pm);
  final_v(x, y, g2, e1, mu, V, Pm);
}

// ---------------------------------------------------------------- output
__global__ void k_out(const float2* __restrict__ frf, const float2* __restrict__ V,
                      const float* __restrict__ Pm, float* __restrict__ out)
{
  const int b2 = blockIdx.x;
  const int t = threadIdx.x & 63;
  const int ng = threadIdx.x >> 6;
  const float4 f = *(const float4*)(frf + ((size_t)b2*64 + t)*2);
  C2 f0, f1; f0.x = f.x; f0.y = f.y; f1.x = f.z; f1.y = f.w;
  for (int n = ng; n < 32; n += 4){
    const float4* mv = (const float4*)(V + ((size_t)n*4096 + b2)*4);
    const float4 m0 = mv[0];
    const float4 m1 = mv[1];
    C2 M00, M01, M10, M11;
    M00.x = m0.x; M00.y = m0.y; M01.x = m0.z; M01.y = m0.w;
    M10.x = m1.x; M10.y = m1.y; M11.x = m1.z; M11.y = m1.w;
    const float sc = 1.41421356237f * rsqrtf(Pm[b2*32 + n]);
    const C2 c0 = cadd(cmul(f0, M00), cmul(f1, M10));
    const C2 c1 = cadd(cmul(f0, M01), cmul(f1, M11));
    const size_t base = (size_t)b2*8192 + n*128 + t*2;
    *(float2*)(out + base)        = make_float2(c0.x*sc, c1.x*sc);
    *(float2*)(out + base + 4096) = make_float2(c0.y*sc, c1.y*sc);
  }
}

// ---------------------------------------------------------------- launch
extern "C" void kernel_launch(void* const* d_in, const int* in_sizes, int n_in,
                              void* d_out, int out_size, void* d_ws, size_t ws_size,
                              hipStream_t stream)
{
  const float* H  = (const float*)d_in[0];
  const float* W0 = (const float*)d_in[1];
  const float* b0 = (const float*)d_in[2];
  const float* W1 = (const float*)d_in[3];
  const float* b1 = (const float*)d_in[4];
  const float* W2 = (const float*)d_in[5];
  const float* b2 = (const float*)d_in[6];
  const float* W3 = (const float*)d_in[7];
  const float* b3 = (const float*)d_in[8];
  float* out = (float*)d_out;
  char* ws = (char*)d_ws;
  (void)in_sizes; (void)n_in; (void)out_size; (void)ws_size;

  size_t o = 0;
  auto alloc = [&](size_t bytes) -> void* {
    void* p = ws + o;
    o += (bytes + 255) & ~(size_t)255;
    return p;
  };
  float2* frf   = (float2*)alloc((size_t)4096*64*2*sizeof(float2)); // 4 MiB
  float2* g2    = (float2*)alloc((size_t)4096*sizeof(float2));
  float*  xbuf  = (float*) alloc((size_t)M2N*8*sizeof(float));      // 4 MiB
  float*  ybuf  = (float*) alloc((size_t)M2N*8*sizeof(float));      // 4 MiB
  float2* V     = (float2*)alloc((size_t)M2N*4*sizeof(float2));     // 4 MiB
  float*  Pm    = (float*) alloc((size_t)M2N*sizeof(float));        // 0.5 MiB
  float*  pr    = (float*) alloc((size_t)2*2048*sizeof(float));     // 16 KiB
  int*    bar   = (int*)   alloc(8*sizeof(int));
  f16*    wfr12 = (f16*)   alloc((size_t)256*1024*sizeof(f16));     // 512 KiB
  f16*    wfr0  = (f16*)   alloc((size_t)16*1024*sizeof(f16));      // 32 KiB
  f16*    wfr3  = (f16*)   alloc((size_t)8*1024*sizeof(f16));       // 16 KiB

  k_prep<<<66, 256, 0, stream>>>(W0, W1, W2, W3, wfr12, wfr0, wfr3, bar);
  k_frf<<<2048, 256, 0, stream>>>(H, frf, g2);
  k_hequ<<<32768, 256, 0, stream>>>(H, frf, xbuf);
  k_mlp<<<2048, 256, 0, stream>>>(xbuf, wfr12, wfr0, wfr3, b0, b1, b2, b3, ybuf);
  {
    void* kargs[] = { (void*)&xbuf, (void*)&ybuf, (void*)&g2, (void*)&pr,
                      (void*)&bar, (void*)&V, (void*)&Pm };
    hipLaunchCooperativeKernel((void*)k_solve, dim3(64), dim3(1024), kargs, 0, stream);
  }
  k_out<<<4096, 256, 0, stream>>>(frf, V, Pm, out);
}

// Round 6
// 307.769 us; speedup vs baseline: 1.5070x; 1.0018x over previous
//
#include <hip/hip_runtime.h>

typedef _Float16 f16;
typedef __attribute__((ext_vector_type(8))) _Float16 f16x8;
typedef __attribute__((ext_vector_type(4))) float f32x4;
typedef unsigned int u32;

#define M2N 131072   // BATCH(4096) * Nc(32)
#define MFMA16 __builtin_amdgcn_mfma_f32_16x16x32_f16

struct C2 { float x, y; };
__device__ __forceinline__ C2 cmul(C2 a, C2 b){ C2 r; r.x = a.x*b.x - a.y*b.y; r.y = a.x*b.y + a.y*b.x; return r; }
__device__ __forceinline__ C2 cadd(C2 a, C2 b){ C2 r; r.x = a.x+b.x; r.y = a.y+b.y; return r; }
__device__ __forceinline__ C2 csub(C2 a, C2 b){ C2 r; r.x = a.x-b.x; r.y = a.y-b.y; return r; }
__device__ __forceinline__ C2 conjc(C2 a){ C2 r; r.x = a.x; r.y = -a.y; return r; }
__device__ __forceinline__ C2 cneg(C2 a){ C2 r; r.x = -a.x; r.y = -a.y; return r; }
__device__ __forceinline__ float cabs2(C2 a){ return a.x*a.x + a.y*a.y; }
__device__ __forceinline__ float dotr(C2 a, C2 b){ return a.x*b.x + a.y*b.y; }

__device__ __forceinline__ float wred(float v){
  #pragma unroll
  for (int s = 32; s > 0; s >>= 1) v += __shfl_xor(v, s, 64);
  return v;
}

// Two-level grid barrier (cooperative launch => co-resident blocks).
// Arrivals split over 8 cachelines (parallel RMW streams), then an 8-way
// group stage. Release/acquire chains through the ACQ_REL RMWs.
// bar layout (ints): group counters at 0,32,...,224; gen at 256; gcnt at 288.
__device__ __forceinline__ void gbarrier(int* bar, int nb){
  __syncthreads();
  if (threadIdx.x == 0){
    int* gen  = bar + 256;
    int* gcnt = bar + 288;
    int* my   = bar + (blockIdx.x & 7)*32;
    const int g = __hip_atomic_load(gen, __ATOMIC_RELAXED, __HIP_MEMORY_SCOPE_AGENT);
    const int a = __hip_atomic_fetch_add(my, 1, __ATOMIC_ACQ_REL, __HIP_MEMORY_SCOPE_AGENT);
    if (a == nb/8 - 1){
      __hip_atomic_store(my, 0, __ATOMIC_RELAXED, __HIP_MEMORY_SCOPE_AGENT);
      const int ga = __hip_atomic_fetch_add(gcnt, 1, __ATOMIC_ACQ_REL, __HIP_MEMORY_SCOPE_AGENT);
      if (ga == 7){
        __hip_atomic_store(gcnt, 0, __ATOMIC_RELAXED, __HIP_MEMORY_SCOPE_AGENT);
        __hip_atomic_store(gen, g + 1, __ATOMIC_RELEASE, __HIP_MEMORY_SCOPE_AGENT);
      } else {
        while (__hip_atomic_load(gen, __ATOMIC_RELAXED, __HIP_MEMORY_SCOPE_AGENT) == g)
          __builtin_amdgcn_s_sleep(4);
        (void)__hip_atomic_load(gen, __ATOMIC_ACQUIRE, __HIP_MEMORY_SCOPE_AGENT);
      }
    } else {
      while (__hip_atomic_load(gen, __ATOMIC_RELAXED, __HIP_MEMORY_SCOPE_AGENT) == g)
        __builtin_amdgcn_s_sleep(4);
      (void)__hip_atomic_load(gen, __ATOMIC_ACQUIRE, __HIP_MEMORY_SCOPE_AGENT);
    }
  }
  __syncthreads();
}

// ---------------------------------------------------------------- prep
// Build frag-linear hi/lo f16 weight fragments for 16x16x32 MFMA.
// B-frag: lane l holds B[k = kt*32 + (l>>4)*8 + e][n = nt*16 + (l&15)].
__global__ void k_prep(const float* __restrict__ W0, const float* __restrict__ W1,
                       const float* __restrict__ W2, const float* __restrict__ W3,
                       f16* __restrict__ wfr12, f16* __restrict__ wfr0,
                       f16* __restrict__ wfr3, int* __restrict__ bar)
{
  const int b = blockIdx.x, tid = threadIdx.x;
  if (b < 64){
    const int slot = b*256 + tid;        // [0, 16384)
    const int lane = slot & 63;
    const int rest = slot >> 6;          // L*128 + nt*8 + kt
    const int kt = rest & 7, nt = (rest >> 3) & 15, L = rest >> 7;
    const float* W = L ? W2 : W1;
    const int n = nt*16 + (lane & 15);
    f16* dst = wfr12 + (size_t)rest*1024 + lane*8;
    #pragma unroll
    for (int e = 0; e < 8; ++e){
      const int k = kt*32 + (lane>>4)*8 + e;
      const float w = W[k*256 + n];
      const f16 h = (f16)w;
      dst[e] = h; dst[512+e] = (f16)(w - (float)h);
    }
  } else if (b == 64){
    for (int i = 0; i < 4; ++i){
      const int slot = i*256 + tid;      // [0,1024)
      const int lane = slot & 63, nt = slot >> 6;
      const int col = nt*16 + (lane & 15);
      f16* dst = wfr0 + (size_t)nt*1024 + lane*8;
      #pragma unroll
      for (int e = 0; e < 8; ++e){
        const int k = (lane>>4)*8 + e;
        const float w = (k < 8) ? W0[k*256 + col] : 0.f;
        const f16 h = (f16)w;
        dst[e] = h; dst[512+e] = (f16)(w - (float)h);
      }
    }
  } else {
    // zero barrier state (512 ints)
    __hip_atomic_store(bar + tid,       0, __ATOMIC_RELAXED, __HIP_MEMORY_SCOPE_AGENT);
    __hip_atomic_store(bar + tid + 256, 0, __ATOMIC_RELAXED, __HIP_MEMORY_SCOPE_AGENT);
    for (int i = 0; i < 2; ++i){
      const int slot = i*256 + tid;      // [0,512)
      const int lane = slot & 63, kt = slot >> 6;
      const int col = lane & 15;
      f16* dst = wfr3 + (size_t)kt*1024 + lane*8;
      #pragma unroll
      for (int e = 0; e < 8; ++e){
        const int k = kt*32 + (lane>>4)*8 + e;
        const float w = (col < 8) ? W3[k*8 + col] : 0.f;
        const f16 h = (f16)w;
        dst[e] = h; dst[512+e] = (f16)(w - (float)h);
      }
    }
  }
}

// ---------------------------------------------------------------- F_RF + g2
__global__ void k_frf(const float* __restrict__ H, float2* __restrict__ frf,
                      float2* __restrict__ g2)
{
  const int b2 = blockIdx.x*2 + (threadIdx.x >> 7);
  const int tt = threadIdx.x & 127;
  const int t = tt >> 1, k = tt & 1;
  __shared__ float2 s[2][128];
  const size_t base = ((size_t)(b2*2 + k)*32 + 16)*128;
  const float are = H[base + t];
  const float aim = H[base];
  const float inv = rsqrtf(are*are + aim*aim) * 0.125f;
  float2 v; v.x = are*inv; v.y = -aim*inv;
  frf[((size_t)b2*64 + t)*2 + k] = v;
  s[threadIdx.x >> 7][tt] = v;
  __syncthreads();
  const int w = threadIdx.x >> 6;
  if ((w & 1) == 0){
    const int half = w >> 1;
    const int lane = threadIdx.x & 63;
    const float2 a = s[half][lane*2];
    const float2 b = s[half][lane*2 + 1];
    float re = a.x*b.x + a.y*b.y;          // a * conj(b)
    float im = a.y*b.x - a.x*b.y;
    re = wred(re); im = wred(im);
    if (lane == 0){ float2 g; g.x = re; g.y = im; g2[blockIdx.x*2 + half] = g; }
  }
}

// ---------------------------------------------------------------- H_equ -> x
__global__ void k_hequ(const float* __restrict__ H, const float2* __restrict__ frf,
                       float* __restrict__ x)
{
  const int m2 = blockIdx.x*4 + (threadIdx.x >> 6);
  const int lane = threadIdx.x & 63;
  const int n = m2 >> 12, b2 = m2 & 4095;
  const float4 f = *(const float4*)(frf + ((size_t)b2*64 + lane)*2);
  float accr[2][2], acci[2][2];
  #pragma unroll
  for (int i = 0; i < 2; ++i){
    const float* hr = H + (size_t)(n*8192 + b2*2 + i) * 128;
    const float re = hr[lane];
    const float im = hr[0];
    accr[i][0] = re*f.x - im*f.y;  acci[i][0] = re*f.y + im*f.x;
    accr[i][1] = re*f.z - im*f.w;  acci[i][1] = re*f.w + im*f.z;
  }
  #pragma unroll
  for (int i = 0; i < 2; ++i)
    #pragma unroll
    for (int j = 0; j < 2; ++j){ accr[i][j] = wred(accr[i][j]); acci[i][j] = wred(acci[i][j]); }
  if (lane == 0){
    float pw = 0.f;
    #pragma unroll
    for (int i = 0; i < 2; ++i)
      #pragma unroll
      for (int j = 0; j < 2; ++j) pw += accr[i][j]*accr[i][j] + acci[i][j]*acci[i][j];
    const float rs = rsqrtf(pw);
    *(float4*)(x + (size_t)m2*8)     = make_float4(accr[0][0]*rs, accr[0][1]*rs, accr[1][0]*rs, accr[1][1]*rs);
    *(float4*)(x + (size_t)m2*8 + 4) = make_float4(acci[0][0]*rs, acci[0][1]*rs, acci[1][0]*rs, acci[1][1]*rs);
  }
}

// ---------------------------------------------------------------- fused MLP
// Two-plane f16 activations in LDS (hi 32KB + lo 32KB): A-fragments are two
// direct ds_read_b128, zero v_perm unpacking. Swizzle at 8-f16 granule.
#define SWX(r, c) ((r)*256 + ((c) ^ (((r)&7)<<3)))

__launch_bounds__(256, 2)
__global__ void k_mlp(const float* __restrict__ x, const f16* __restrict__ wfr12,
                      const f16* __restrict__ wfr0, const f16* __restrict__ wfr3,
                      const float* __restrict__ bias0, const float* __restrict__ bias1,
                      const float* __restrict__ bias2, const float* __restrict__ bias3,
                      float* __restrict__ y)
{
  __shared__ __align__(16) f16 xah[64*256];   // 32 KiB
  __shared__ __align__(16) f16 xal[64*256];   // 32 KiB
  const int tid = threadIdx.x, blk = blockIdx.x;
  const int lane = tid & 63, wv = tid >> 6;
  const int l15 = lane & 15, lh = lane >> 4;

  f32x4 acc[4][4];
  f16x8 ah[4], al[4], bh[4], bl[4];

  auto EPI = [&](){   // relu + exact f16 split + two-plane swizzled LDS write
    #pragma unroll
    for (int Mt = 0; Mt < 4; ++Mt)
      #pragma unroll
      for (int nt = 0; nt < 4; ++nt)
        #pragma unroll
        for (int r = 0; r < 4; ++r){
          const float v = fmaxf(acc[Mt][nt][r], 0.f);
          const f16 h = (f16)v;
          const f16 lo16 = (f16)(v - (float)h);
          const int row = Mt*16 + lh*4 + r;
          const int col = wv*64 + nt*16 + l15;
          const int idx = SWX(row, col);
          xah[idx] = h;
          xal[idx] = lo16;
        }
  };

  // ---------- layer 0 (8 -> 256, K padded to 32; zero-padded B kills garbage A)
  #pragma unroll
  for (int nt = 0; nt < 4; ++nt){
    const float bb = bias0[wv*64 + nt*16 + l15];
    f32x4 v = {bb,bb,bb,bb};
    #pragma unroll
    for (int Mt = 0; Mt < 4; ++Mt) acc[Mt][nt] = v;
  }
  #pragma unroll
  for (int Mt = 0; Mt < 4; ++Mt){
    const float* xr = x + ((size_t)blk*64 + Mt*16 + l15)*8;
    const float4 v0 = *(const float4*)xr;
    const float4 v1 = *(const float4*)(xr+4);
    const float vv[8] = {v0.x,v0.y,v0.z,v0.w,v1.x,v1.y,v1.z,v1.w};
    #pragma unroll
    for (int e = 0; e < 8; ++e){
      const f16 h = (f16)vv[e];
      ah[Mt][e] = h; al[Mt][e] = (f16)(vv[e] - (float)h);
    }
  }
  #pragma unroll
  for (int nt = 0; nt < 4; ++nt){
    bh[nt] = *(const f16x8*)(wfr0 + (size_t)(wv*4+nt)*1024 + lane*8);
    bl[nt] = *(const f16x8*)(wfr0 + (size_t)(wv*4+nt)*1024 + 512 + lane*8);
  }
  #pragma unroll
  for (int Mt = 0; Mt < 4; ++Mt)
    #pragma unroll
    for (int nt = 0; nt < 4; ++nt){
      acc[Mt][nt] = MFMA16(ah[Mt], bh[nt], acc[Mt][nt], 0, 0, 0);
      acc[Mt][nt] = MFMA16(al[Mt], bh[nt], acc[Mt][nt], 0, 0, 0);
      acc[Mt][nt] = MFMA16(ah[Mt], bl[nt], acc[Mt][nt], 0, 0, 0);
    }
  EPI();
  __syncthreads();

  // ---------- layers 1,2 (256 -> 256)
  for (int L = 0; L < 2; ++L){
    const float* bs = L ? bias2 : bias1;
    #pragma unroll
    for (int nt = 0; nt < 4; ++nt){
      const float bb = bs[wv*64 + nt*16 + l15];
      f32x4 v = {bb,bb,bb,bb};
      #pragma unroll
      for (int Mt = 0; Mt < 4; ++Mt) acc[Mt][nt] = v;
    }
    #pragma unroll 2
    for (int kt = 0; kt < 8; ++kt){
      #pragma unroll
      for (int Mt = 0; Mt < 4; ++Mt){
        const int idx = SWX(Mt*16 + l15, kt*32 + lh*8);
        ah[Mt] = *(const f16x8*)(xah + idx);
        al[Mt] = *(const f16x8*)(xal + idx);
      }
      #pragma unroll
      for (int nt = 0; nt < 4; ++nt){
        const size_t f = ((size_t)(L*128 + (wv*4+nt)*8 + kt))*1024;
        bh[nt] = *(const f16x8*)(wfr12 + f + lane*8);
        bl[nt] = *(const f16x8*)(wfr12 + f + 512 + lane*8);
      }
      #pragma unroll
      for (int Mt = 0; Mt < 4; ++Mt)
        #pragma unroll
        for (int nt = 0; nt < 4; ++nt){
          acc[Mt][nt] = MFMA16(ah[Mt], bh[nt], acc[Mt][nt], 0, 0, 0);
          acc[Mt][nt] = MFMA16(al[Mt], bh[nt], acc[Mt][nt], 0, 0, 0);
          acc[Mt][nt] = MFMA16(ah[Mt], bl[nt], acc[Mt][nt], 0, 0, 0);
        }
    }
    __syncthreads();   // all reads done before overwrite
    EPI();
    __syncthreads();
  }

  // ---------- layer 3 (256 -> 8, N padded to 16; zero-padded B cols)
  f32x4 a3[4];
  {
    const float bb = (l15 < 8) ? bias3[l15] : 0.f;
    f32x4 v = {bb,bb,bb,bb};
    #pragma unroll
    for (int Mt = 0; Mt < 4; ++Mt) a3[Mt] = v;
  }
  #pragma unroll 2
  for (int kt = 0; kt < 8; ++kt){
    #pragma unroll
    for (int Mt = 0; Mt < 4; ++Mt){
      const int idx = SWX(Mt*16 + l15, kt*32 + lh*8);
      ah[Mt] = *(const f16x8*)(xah + idx);
      al[Mt] = *(const f16x8*)(xal + idx);
    }
    const f16x8 b3h = *(const f16x8*)(wfr3 + (size_t)kt*1024 + lane*8);
    const f16x8 b3l = *(const f16x8*)(wfr3 + (size_t)kt*1024 + 512 + lane*8);
    #pragma unroll
    for (int Mt = 0; Mt < 4; ++Mt){
      a3[Mt] = MFMA16(ah[Mt], b3h, a3[Mt], 0, 0, 0);
      a3[Mt] = MFMA16(al[Mt], b3h, a3[Mt], 0, 0, 0);
      a3[Mt] = MFMA16(ah[Mt], b3l, a3[Mt], 0, 0, 0);
    }
  }
  if (l15 < 8){
    #pragma unroll
    for (int Mt = 0; Mt < 4; ++Mt)
      #pragma unroll
      for (int r = 0; r < 4; ++r)
        y[((size_t)blk*64 + Mt*16 + lh*4 + r)*8 + l15] = a3[Mt][r];
  }
}

// ---------------------------------------------------------------- per-element algebra
struct Elem {
  C2 p[2][2], g[2][2], UW[2], d0, d1;
  float A0, A1, A2, c0, c1, c2, c3;
};
struct Coef { float A0, A1, A2, c0, c1, c2, c3; };

__device__ __forceinline__ void elem_core(const float* __restrict__ x,
                                          const float* __restrict__ y,
                                          int gid, Elem& E)
{
  const float4 xr = *(const float4*)(x + (size_t)gid*8);
  const float4 xi = *(const float4*)(x + (size_t)gid*8 + 4);
  C2 h[2][2];
  h[0][0].x = xr.x; h[0][0].y = xi.x; h[0][1].x = xr.y; h[0][1].y = xi.y;
  h[1][0].x = xr.z; h[1][0].y = xi.z; h[1][1].x = xr.w; h[1][1].y = xi.w;
  const float4 ya = *(const float4*)(y + (size_t)gid*8);
  const float4 yb = *(const float4*)(y + (size_t)gid*8 + 4);
  C2 U[2], Wm[2];
  U[0].x = ya.x; U[0].y = ya.z;  U[1].x = ya.y; U[1].y = ya.w;
  Wm[0].x = yb.x; Wm[0].y = yb.z; Wm[1].x = yb.y; Wm[1].y = yb.w;
  const float u20 = cabs2(U[0]), u21 = cabs2(U[1]);
  C2 cf[2];
  cf[0].x = Wm[0].x*u20; cf[0].y = Wm[0].y*u20;
  cf[1].x = Wm[1].x*u21; cf[1].y = Wm[1].y*u21;
  C2 B[2][2];
  #pragma unroll
  for (int i = 0; i < 2; ++i)
    #pragma unroll
    for (int j = 0; j < 2; ++j){
      const C2 t0 = cmul(conjc(h[0][i]), h[0][j]);
      const C2 t1 = cmul(conjc(h[1][i]), h[1][j]);
      B[i][j] = cadd(cmul(cf[0], t0), cmul(cf[1], t1));
    }
  C2 adj[2][2];
  adj[0][0] = B[1][1]; adj[0][1] = cneg(B[0][1]);
  adj[1][0] = cneg(B[1][0]); adj[1][1] = B[0][0];
  E.d0 = csub(cmul(B[0][0], B[1][1]), cmul(B[0][1], B[1][0]));
  E.d1.x = 2.f*(B[0][0].x + B[1][1].x);
  E.d1.y = 2.f*(B[0][0].y + B[1][1].y);
  #pragma unroll
  for (int k = 0; k < 2; ++k){
    #pragma unroll
    for (int j = 0; j < 2; ++j) E.g[k][j] = conjc(h[k][j]);
    #pragma unroll
    for (int i = 0; i < 2; ++i)
      E.p[k][i] = cadd(cmul(adj[i][0], E.g[k][0]), cmul(adj[i][1], E.g[k][1]));
    E.UW[k] = cmul(U[k], Wm[k]);
  }
  const float w0 = cabs2(E.UW[0]), w1 = cabs2(E.UW[1]);
  E.A0 = w0*(cabs2(E.p[0][0]) + cabs2(E.p[0][1])) + w1*(cabs2(E.p[1][0]) + cabs2(E.p[1][1]));
  E.A1 = 4.f*( w0*(dotr(E.p[0][0], E.g[0][0]) + dotr(E.p[0][1], E.g[0][1]))
             + w1*(dotr(E.p[1][0], E.g[1][0]) + dotr(E.p[1][1], E.g[1][1])) );
  E.A2 = 4.f*( w0*(cabs2(E.g[0][0]) + cabs2(E.g[0][1]))
             + w1*(cabs2(E.g[1][0]) + cabs2(E.g[1][1])) );
  E.c0 = cabs2(E.d0);
  E.c1 = 2.f*(E.d0.x*E.d1.x + E.d0.y*E.d1.y);
  E.c2 = cabs2(E.d1) + 8.f*E.d0.x;
  E.c3 = 8.f*E.d1.x;
}

__device__ __forceinline__ float evalf(float mu, const Coef& C){
  const float num = C.A0 + mu*(C.A1 + mu*C.A2);
  const float den = C.c0 + mu*(C.c1 + mu*(C.c2 + mu*(C.c3 + mu*16.f)));
  return num/den;
}

// One multi-level bisection round: evaluate the full depth-LV candidate
// subtree ((1<<LV)-1 mus, bit-exact sequential midpoints via heap recursion),
// one grid barrier, then walk LV decisions.
template<int LV>
__device__ __forceinline__ void bis_round(float& lo, float& hi, const Coef& C,
                                          float* __restrict__ pr, int* __restrict__ bar,
                                          int buf, int blk, int nb,
                                          float (*r8)[32], float* tot)
{
  constexpr int NN = (1 << LV) - 1;
  const int tid = threadIdx.x;
  const int lane = tid & 63, wv = tid >> 6;

  float nl[NN], nh[NN], cn[NN];
  nl[0] = lo; nh[0] = hi;
  #pragma unroll
  for (int i = 0; i < NN; ++i){
    cn[i] = 0.5f*(nl[i] + nh[i]);
    if (2*i + 2 < NN){
      nl[2*i+1] = nl[i]; nh[2*i+1] = cn[i];
      nl[2*i+2] = cn[i]; nh[2*i+2] = nh[i];
    }
  }
  #pragma unroll
  for (int q = 0; q < NN; ++q){
    const float f = wred(evalf(cn[q], C));
    if (lane == 0) r8[wv][q] = f;
  }
  __syncthreads();
  if (tid < NN){
    float s = 0.f;
    #pragma unroll
    for (int w = 0; w < 8; ++w) s += r8[w][tid];
    pr[buf*8192 + blk*32 + tid] = s;
  }
  gbarrier(bar, nb);
  {
    const int q = tid >> 4, sub = tid & 15;
    if (q < NN){
      float s = 0.f;
      #pragma unroll
      for (int j = 0; j < 16; ++j) s += pr[buf*8192 + (sub + j*16)*32 + q];
      #pragma unroll
      for (int d = 8; d > 0; d >>= 1) s += __shfl_xor(s, d, 64);
      if (sub == 0) tot[q] = s;
    }
  }
  __syncthreads();
  int i = 0;
  #pragma unroll
  for (int d = 0; d < LV; ++d){
    const float mu = 0.5f*(lo + hi);     // == cn[i] bit-exactly
    const bool big = tot[i] > 1.0f;
    lo = big ? mu : lo;
    hi = big ? hi : mu;
    i = 2*i + 1 + (big ? 1 : 0);
  }
  __syncthreads();
}

__device__ __forceinline__ void final_v(const float* __restrict__ x,
                                        const float* __restrict__ y,
                                        const float2* __restrict__ g2,
                                        int gid, float mu,
                                        float2* __restrict__ V, float* __restrict__ Pm)
{
  Elem E;
  elem_core(x, y, gid, E);
  C2 det; det.x = E.d0.x + mu*E.d1.x + 4.f*mu*mu; det.y = E.d0.y + mu*E.d1.y;
  const float id = 1.f/cabs2(det);
  C2 idet; idet.x = det.x*id; idet.y = -det.y*id;
  C2 Vv[2][2];
  #pragma unroll
  for (int k = 0; k < 2; ++k)
    #pragma unroll
    for (int i = 0; i < 2; ++i){
      C2 t; t.x = E.p[k][i].x + 2.f*mu*E.g[k][i].x; t.y = E.p[k][i].y + 2.f*mu*E.g[k][i].y;
      Vv[i][k] = cmul(E.UW[k], cmul(t, idet));
    }
  *(float4*)(V + (size_t)gid*4)     = make_float4(Vv[0][0].x, Vv[0][0].y, Vv[0][1].x, Vv[0][1].y);
  *(float4*)(V + (size_t)gid*4 + 2) = make_float4(Vv[1][0].x, Vv[1][0].y, Vv[1][1].x, Vv[1][1].y);
  const float2 gg2 = g2[gid & 4095];
  C2 gc; gc.x = gg2.x; gc.y = gg2.y;
  float P = 0.f;
  #pragma unroll
  for (int k = 0; k < 2; ++k){
    const C2 a = Vv[0][k], b = Vv[1][k];
    P += cabs2(a) + cabs2(b);
    const C2 t = cmul(gc, cmul(a, conjc(b)));
    P += 2.f*t.x;
  }
  Pm[gid] = P;
}

// ---------------------------------------------------------------- fused bisection solve
// 256 blocks x 512 thr (cooperative), 1 element/thread. 4 barriers:
// rounds of 5+5+5+4 levels. Double-buffered block partials.
__launch_bounds__(512)
__global__ void k_solve(const float* __restrict__ x, const float* __restrict__ y,
                        const float2* __restrict__ g2, float* __restrict__ pr,
                        int* __restrict__ bar, float2* __restrict__ V,
                        float* __restrict__ Pm)
{
  const int tid = threadIdx.x, blk = blockIdx.x;
  const int nb = gridDim.x;
  const int gid = blk*512 + tid;
  __shared__ float r8[8][32];
  __shared__ float tot[32];

  Coef C;
  { Elem E; elem_core(x, y, gid, E);
    C.A0=E.A0; C.A1=E.A1; C.A2=E.A2; C.c0=E.c0; C.c1=E.c1; C.c2=E.c2; C.c3=E.c3; }

  float lo = 0.f, hi = 10.f;
  bis_round<5>(lo, hi, C, pr, bar, 0, blk, nb, r8, tot);
  bis_round<5>(lo, hi, C, pr, bar, 1, blk, nb, r8, tot);
  bis_round<5>(lo, hi, C, pr, bar, 0, blk, nb, r8, tot);
  bis_round<4>(lo, hi, C, pr, bar, 1, blk, nb, r8, tot);

  const float mu = 0.5f*(lo + hi);   // 20th midpoint, as in reference
  final_v(x, y, g2, gid, mu, V, Pm);
}

// ---------------------------------------------------------------- output
__global__ void k_out(const float2* __restrict__ frf, const float2* __restrict__ V,
                      const float* __restrict__ Pm, float* __restrict__ out)
{
  const int b2 = blockIdx.x;
  const int t = threadIdx.x & 63;
  const int ng = threadIdx.x >> 6;
  const float4 f = *(const float4*)(frf + ((size_t)b2*64 + t)*2);
  C2 f0, f1; f0.x = f.x; f0.y = f.y; f1.x = f.z; f1.y = f.w;
  for (int n = ng; n < 32; n += 4){
    const float4* mv = (const float4*)(V + ((size_t)n*4096 + b2)*4);
    const float4 m0 = mv[0];
    const float4 m1 = mv[1];
    C2 M00, M01, M10, M11;
    M00.x = m0.x; M00.y = m0.y; M01.x = m0.z; M01.y = m0.w;
    M10.x = m1.x; M10.y = m1.y; M11.x = m1.z; M11.y = m1.w;
    const float sc = 1.41421356237f * rsqrtf(Pm[b2*32 + n]);
    const C2 c0 = cadd(cmul(f0, M00), cmul(f1, M10));
    const C2 c1 = cadd(cmul(f0, M01), cmul(f1, M11));
    const size_t base = (size_t)b2*8192 + n*128 + t*2;
    *(float2*)(out + base)        = make_float2(c0.x*sc, c1.x*sc);
    *(float2*)(out + base + 4096) = make_float2(c0.y*sc, c1.y*sc);
  }
}

// ---------------------------------------------------------------- launch
extern "C" void kernel_launch(void* const* d_in, const int* in_sizes, int n_in,
                              void* d_out, int out_size, void* d_ws, size_t ws_size,
                              hipStream_t stream)
{
  const float* H  = (const float*)d_in[0];
  const float* W0 = (const float*)d_in[1];
  const float* b0 = (const float*)d_in[2];
  const float* W1 = (const float*)d_in[3];
  const float* b1 = (const float*)d_in[4];
  const float* W2 = (const float*)d_in[5];
  const float* b2 = (const float*)d_in[6];
  const float* W3 = (const float*)d_in[7];
  const float* b3 = (const float*)d_in[8];
  float* out = (float*)d_out;
  char* ws = (char*)d_ws;
  (void)in_sizes; (void)n_in; (void)out_size; (void)ws_size;

  size_t o = 0;
  auto alloc = [&](size_t bytes) -> void* {
    void* p = ws + o;
    o += (bytes + 255) & ~(size_t)255;
    return p;
  };
  float2* frf   = (float2*)alloc((size_t)4096*64*2*sizeof(float2)); // 4 MiB
  float2* g2    = (float2*)alloc((size_t)4096*sizeof(float2));
  float*  xbuf  = (float*) alloc((size_t)M2N*8*sizeof(float));      // 4 MiB
  float*  ybuf  = (float*) alloc((size_t)M2N*8*sizeof(float));      // 4 MiB
  float2* V     = (float2*)alloc((size_t)M2N*4*sizeof(float2));     // 4 MiB
  float*  Pm    = (float*) alloc((size_t)M2N*sizeof(float));        // 0.5 MiB
  float*  pr    = (float*) alloc((size_t)2*8192*sizeof(float));     // 64 KiB
  int*    bar   = (int*)   alloc(512*sizeof(int));                  // 2 KiB
  f16*    wfr12 = (f16*)   alloc((size_t)256*1024*sizeof(f16));     // 512 KiB
  f16*    wfr0  = (f16*)   alloc((size_t)16*1024*sizeof(f16));      // 32 KiB
  f16*    wfr3  = (f16*)   alloc((size_t)8*1024*sizeof(f16));       // 16 KiB

  k_prep<<<66, 256, 0, stream>>>(W0, W1, W2, W3, wfr12, wfr0, wfr3, bar);
  k_frf<<<2048, 256, 0, stream>>>(H, frf, g2);
  k_hequ<<<32768, 256, 0, stream>>>(H, frf, xbuf);
  k_mlp<<<2048, 256, 0, stream>>>(xbuf, wfr12, wfr0, wfr3, b0, b1, b2, b3, ybuf);
  {
    void* kargs[] = { (void*)&xbuf, (void*)&ybuf, (void*)&g2, (void*)&pr,
                      (void*)&bar, (void*)&V, (void*)&Pm };
    hipLaunchCooperativeKernel((void*)k_solve, dim3(256), dim3(512), kargs, 0, stream);
  }
  k_out<<<4096, 256, 0, stream>>>(frf, V, Pm, out);
}